// Round 2
// baseline (504.279 us; speedup 1.0000x reference)
//
#include <hip/hip_runtime.h>

typedef unsigned short u16;
typedef u16   u16x4 __attribute__((ext_vector_type(4)));
typedef u16   u16x8 __attribute__((ext_vector_type(8)));
typedef short s16x8 __attribute__((ext_vector_type(8)));
typedef float f32x4 __attribute__((ext_vector_type(4)));

__device__ __forceinline__ float b2f(u16 u) {
    union { unsigned int i; float f; } v; v.i = ((unsigned int)u) << 16; return v.f;
}
__device__ __forceinline__ u16 f2b(float f) {
    union { float f; unsigned int i; } v; v.f = f;
    unsigned int r = v.i + 0x7fffu + ((v.i >> 16) & 1u);
    return (u16)(r >> 16);
}
__device__ __forceinline__ float gelu_f(float x) {
    float z = 0.7978845608028654f * (x + 0.044715f * x * x * x);
    float e = __expf(2.0f * z);
    float t = 1.0f - 2.0f / (e + 1.0f);
    return 0.5f * x * (1.0f + t);
}
__device__ __forceinline__ void async16(const u16* g, u16* l) {
    __builtin_amdgcn_global_load_lds(
        (const __attribute__((address_space(1))) unsigned int*)g,
        (__attribute__((address_space(3))) unsigned int*)l,
        16, 0, 0);
}

// ---- dtype detector: bf16-read exponent >= 2^60 anywhere => fp32 input
// 32 blocks x 256 threads x u16x8 = 65536 elements, one 16B coalesced load
// per thread, wave-ballot + one atomicOr per wave. (flag memset to 0 first.)
__global__ __launch_bounds__(256)
void detect_k(const u16* __restrict__ x, int* __restrict__ flag)
{
    int gid = blockIdx.x * 256 + threadIdx.x;
    const u16x8 u = *(const u16x8*)(x + (long)gid * 8);
    int bad = 0;
    #pragma unroll
    for (int e = 0; e < 8; e++) {
        int ex = (u[e] >> 7) & 0xFF;
        if (ex >= 187) bad = 1;
    }
    unsigned long long m = __ballot(bad != 0);
    if ((threadIdx.x & 63) == 0 && m != 0ull) atomicOr(flag, 1);
}

// ---- weight converter (vec4): w_in|w_out|w_fc|w_proj -> ws[4Mi..16Mi)
__global__ __launch_bounds__(256)
void conv_w_k(const void* __restrict__ s0, const void* __restrict__ s1,
              const void* __restrict__ s2, const void* __restrict__ s3,
              u16* __restrict__ dst, const int* __restrict__ flag)
{
    const long MEG = 1L << 20;
    long gid = ((long)blockIdx.x * 256 + threadIdx.x) * 4;   // < 12Mi
    const void* s; long off;
    if      (gid <  3*MEG) { s = s0; off = gid; }
    else if (gid <  4*MEG) { s = s1; off = gid - 3*MEG; }
    else if (gid <  8*MEG) { s = s2; off = gid - 4*MEG; }
    else                   { s = s3; off = gid - 8*MEG; }
    u16x4 o;
    if (*flag) {
        const float4 f = *(const float4*)((const float*)s + off);
        o[0] = f2b(f.x); o[1] = f2b(f.y); o[2] = f2b(f.z); o[3] = f2b(f.w);
    } else {
        o = *(const u16x4*)((const u16*)s + off);
    }
    *(u16x4*)(dst + gid) = o;
}

// ---- fused small-param converter into 4Ki-slotted region
__global__ __launch_bounds__(256)
void conv_small_k(const void* s0, const void* s1, const void* s2, const void* s3,
                  const void* s4, const void* s5, const void* s6, const void* s7,
                  u16* __restrict__ dst, const int* __restrict__ flag)
{
    int gid = blockIdx.x * 256 + threadIdx.x;          // < 13312
    int seg, off;
    if      (gid <  4096) { seg = gid >> 10;  off = gid & 1023; }
    else if (gid <  7168) { seg = 4; off = gid - 4096; }
    else if (gid <  8192) { seg = 5; off = gid - 7168; }
    else if (gid < 12288) { seg = 6; off = gid - 8192; }
    else                  { seg = 7; off = gid - 12288; }
    const void* srcs[8] = {s0, s1, s2, s3, s4, s5, s6, s7};
    const void* s = srcs[seg];
    dst[seg * 4096 + off] = (*flag) ? f2b(((const float*)s)[off]) : ((const u16*)s)[off];
}

// ---- LN1 fused with x conversion
__global__ __launch_bounds__(256)
void ln1x_k(const void* __restrict__ xraw, const u16* __restrict__ g,
            const u16* __restrict__ b, u16* __restrict__ xc,
            u16* __restrict__ o, const int* __restrict__ flag)
{
    long row = blockIdx.x;
    int tid = threadIdx.x;
    float v0, v1, v2, v3;
    if (*flag) {
        const float4 f = *(const float4*)((const float*)xraw + row * 1024 + tid * 4);
        v0 = b2f(f2b(f.x)); v1 = b2f(f2b(f.y));
        v2 = b2f(f2b(f.z)); v3 = b2f(f2b(f.w));
    } else {
        const u16x4 u = *(const u16x4*)((const u16*)xraw + row * 1024 + tid * 4);
        v0 = b2f(u[0]); v1 = b2f(u[1]); v2 = b2f(u[2]); v3 = b2f(u[3]);
    }
    u16x4 xv; xv[0] = f2b(v0); xv[1] = f2b(v1); xv[2] = f2b(v2); xv[3] = f2b(v3);
    *(u16x4*)(xc + row * 1024 + tid * 4) = xv;
    float s  = v0 + v1 + v2 + v3;
    float sq = v0*v0 + v1*v1 + v2*v2 + v3*v3;
    #pragma unroll
    for (int off = 32; off; off >>= 1) { s += __shfl_xor(s, off); sq += __shfl_xor(sq, off); }
    __shared__ float sm[8];
    int wid = tid >> 6, lane = tid & 63;
    if (lane == 0) { sm[wid] = s; sm[wid + 4] = sq; }
    __syncthreads();
    s  = sm[0] + sm[1] + sm[2] + sm[3];
    sq = sm[4] + sm[5] + sm[6] + sm[7];
    float mean = s * (1.0f / 1024.0f);
    float var  = sq * (1.0f / 1024.0f) - mean * mean;
    float rs   = rsqrtf(var + 1e-5f);
    u16x4 gg = *(const u16x4*)(g + tid * 4);
    u16x4 bb = *(const u16x4*)(b + tid * 4);
    u16x4 ov;
    ov[0] = f2b((v0 - mean) * rs * b2f(gg[0]) + b2f(bb[0]));
    ov[1] = f2b((v1 - mean) * rs * b2f(gg[1]) + b2f(bb[1]));
    ov[2] = f2b((v2 - mean) * rs * b2f(gg[2]) + b2f(bb[2]));
    ov[3] = f2b((v3 - mean) * rs * b2f(gg[3]) + b2f(bb[3]));
    *(u16x4*)(o + row * 1024 + tid * 4) = ov;
}

// ---- plain LN (fallback path)
__global__ __launch_bounds__(256)
void ln_k(const u16* __restrict__ x, const u16* __restrict__ g,
          const u16* __restrict__ b, u16* __restrict__ o)
{
    long row = blockIdx.x;
    int tid = threadIdx.x;
    const u16x4 u = *(const u16x4*)(x + row * 1024 + tid * 4);
    float v0 = b2f(u[0]), v1 = b2f(u[1]), v2 = b2f(u[2]), v3 = b2f(u[3]);
    float s  = v0 + v1 + v2 + v3;
    float sq = v0*v0 + v1*v1 + v2*v2 + v3*v3;
    #pragma unroll
    for (int off = 32; off; off >>= 1) { s += __shfl_xor(s, off); sq += __shfl_xor(sq, off); }
    __shared__ float sm[8];
    int wid = tid >> 6, lane = tid & 63;
    if (lane == 0) { sm[wid] = s; sm[wid + 4] = sq; }
    __syncthreads();
    s  = sm[0] + sm[1] + sm[2] + sm[3];
    sq = sm[4] + sm[5] + sm[6] + sm[7];
    float mean = s * (1.0f / 1024.0f);
    float var  = sq * (1.0f / 1024.0f) - mean * mean;
    float rs   = rsqrtf(var + 1e-5f);
    u16x4 gg = *(const u16x4*)(g + tid * 4);
    u16x4 bb = *(const u16x4*)(b + tid * 4);
    u16x4 ov;
    ov[0] = f2b((v0 - mean) * rs * b2f(gg[0]) + b2f(bb[0]));
    ov[1] = f2b((v1 - mean) * rs * b2f(gg[1]) + b2f(bb[1]));
    ov[2] = f2b((v2 - mean) * rs * b2f(gg[2]) + b2f(bb[2]));
    ov[3] = f2b((v3 - mean) * rs * b2f(gg[3]) + b2f(bb[3]));
    *(u16x4*)(o + row * 1024 + tid * 4) = ov;
}

// ---- fused split-K(2) reduce + LN2
__global__ __launch_bounds__(256)
void redln_k(const float* __restrict__ P, long slice,
             const u16* __restrict__ bias, u16* __restrict__ res,
             const u16* __restrict__ g, const u16* __restrict__ b,
             u16* __restrict__ o)
{
    long row = blockIdx.x;
    int tid = threadIdx.x;
    long i = row * 1024 + tid * 4;
    float4 v  = *(const float4*)(P + i);
    float4 p1 = *(const float4*)(P + slice + i);
    u16x4 bb = *(const u16x4*)(bias + tid * 4);
    u16x4 rr = *(const u16x4*)(res + i);
    float v0 = b2f(f2b(v.x + p1.x + b2f(bb[0]) + b2f(rr[0])));
    float v1 = b2f(f2b(v.y + p1.y + b2f(bb[1]) + b2f(rr[1])));
    float v2 = b2f(f2b(v.z + p1.z + b2f(bb[2]) + b2f(rr[2])));
    float v3 = b2f(f2b(v.w + p1.w + b2f(bb[3]) + b2f(rr[3])));
    u16x4 xv; xv[0] = f2b(v0); xv[1] = f2b(v1); xv[2] = f2b(v2); xv[3] = f2b(v3);
    *(u16x4*)(res + i) = xv;
    float s  = v0 + v1 + v2 + v3;
    float sq = v0*v0 + v1*v1 + v2*v2 + v3*v3;
    #pragma unroll
    for (int off = 32; off; off >>= 1) { s += __shfl_xor(s, off); sq += __shfl_xor(sq, off); }
    __shared__ float sm[8];
    int wid = tid >> 6, lane = tid & 63;
    if (lane == 0) { sm[wid] = s; sm[wid + 4] = sq; }
    __syncthreads();
    s  = sm[0] + sm[1] + sm[2] + sm[3];
    sq = sm[4] + sm[5] + sm[6] + sm[7];
    float mean = s * (1.0f / 1024.0f);
    float var  = sq * (1.0f / 1024.0f) - mean * mean;
    float rs   = rsqrtf(var + 1e-5f);
    u16x4 gg = *(const u16x4*)(g + tid * 4);
    u16x4 b2 = *(const u16x4*)(b + tid * 4);
    u16x4 ov;
    ov[0] = f2b((v0 - mean) * rs * b2f(gg[0]) + b2f(b2[0]));
    ov[1] = f2b((v1 - mean) * rs * b2f(gg[1]) + b2f(b2[1]));
    ov[2] = f2b((v2 - mean) * rs * b2f(gg[2]) + b2f(b2[2]));
    ov[3] = f2b((v3 - mean) * rs * b2f(gg[3]) + b2f(b2[3]));
    *(u16x4*)(o + row * 1024 + tid * 4) = ov;
}

// -------- Fused softmax (causal, in-place) + mean-over-heads ----------
__global__ __launch_bounds__(1024)
void smmean_k(u16* __restrict__ probs, void* __restrict__ ow, long ofs,
              const int* __restrict__ flag)
{
    const long MEG = 1L << 20;
    __shared__ float red[16 * 1024];
    int bl = blockIdx.x >> 10;           // batch within chunk
    int q  = blockIdx.x & 1023;
    int w = threadIdx.x >> 6, lane = threadIdx.x & 63;
    int tile_end = ((q >> 7) + 1) << 7;
    u16* row = probs + (((long)(bl * 16 + w)) << 20) + (long)q * 1024;
    float v[16];
    float m = -3.0e38f;
    #pragma unroll
    for (int c = 0; c < 2; c++) {
        int kb = (c * 64 + lane) * 8;
        if (kb <= q) {
            u16x8 u = *(const u16x8*)(row + kb);
            #pragma unroll
            for (int e = 0; e < 8; e++) {
                if (kb + e <= q) {
                    float f = b2f(u[e]);
                    v[c * 8 + e] = f;
                    m = fmaxf(m, f);
                } else v[c * 8 + e] = -3.0e38f;
            }
        } else {
            #pragma unroll
            for (int e = 0; e < 8; e++) v[c * 8 + e] = -3.0e38f;
        }
    }
    #pragma unroll
    for (int off = 32; off; off >>= 1) m = fmaxf(m, __shfl_xor(m, off));
    float s = 0.0f;
    #pragma unroll
    for (int t = 0; t < 16; t++) {
        float e = (v[t] > -1.0e38f) ? __expf(v[t] - m) : 0.0f;
        v[t] = e; s += e;
    }
    #pragma unroll
    for (int off = 32; off; off >>= 1) s += __shfl_xor(s, off);
    float inv = 1.0f / s;
    #pragma unroll
    for (int c = 0; c < 2; c++) {
        int kb = (c * 64 + lane) * 8;
        float p[8];
        #pragma unroll
        for (int e = 0; e < 8; e++) p[e] = v[c * 8 + e] * inv;
        #pragma unroll
        for (int e = 0; e < 8; e++) red[w * 1024 + kb + e] = p[e];
        if (kb < tile_end) {
            u16x8 o;
            #pragma unroll
            for (int e = 0; e < 8; e++) o[e] = f2b(p[e]);
            *(u16x8*)(row + kb) = o;
        }
    }
    __syncthreads();
    int t = threadIdx.x;
    float acc = 0.0f;
    #pragma unroll
    for (int h = 0; h < 16; h++) acc += red[h * 1024 + t];
    acc *= 0.0625f;
    long idx = ofs + (long)bl * MEG + (long)q * 1024 + t;
    if (*flag) ((float*)ow)[idx] = acc;
    else       ((u16*)ow)[idx]   = f2b(acc);
}

// -------- split-K(4) reduce for final output --------
__global__ __launch_bounds__(256)
void reduce_out_k(const float* __restrict__ P, long slice,
                  const u16* __restrict__ bias, const u16* __restrict__ res,
                  void* __restrict__ out, const int* __restrict__ flag)
{
    long i = ((long)blockIdx.x * 256 + threadIdx.x) * 4;
    int gn = (int)(i & 1023);
    float4 v = *(const float4*)(P + i);
    #pragma unroll
    for (int s = 1; s < 4; s++) {
        const float4 p = *(const float4*)(P + (long)s * slice + i);
        v.x += p.x; v.y += p.y; v.z += p.z; v.w += p.w;
    }
    u16x4 bb = *(const u16x4*)(bias + gn);
    u16x4 rr = *(const u16x4*)(res + i);
    v.x += b2f(bb[0]) + b2f(rr[0]);
    v.y += b2f(bb[1]) + b2f(rr[1]);
    v.z += b2f(bb[2]) + b2f(rr[2]);
    v.w += b2f(bb[3]) + b2f(rr[3]);
    if (*flag) {
        *(float4*)((float*)out + i) = v;
    } else {
        u16x4 o;
        o[0] = f2b(v.x); o[1] = f2b(v.y); o[2] = f2b(v.z); o[3] = f2b(v.w);
        *(u16x4*)((u16*)out + i) = o;
    }
}

// ---------------- gemm_bt: C[m,n] = sum_k A[m,k]*Bt[n,k] + epilogue ---
// EPI: 1 qkv-routing (+bias, v via LDS transpose), 2 +bias+residual,
//      3 gelu(+bias), 4 scores (scale+causal), 5 PV (k-limit),
//      6 +bias+residual flag-adaptive, 7 split-K fp32 partial
//
// LDS staging is FRAGMENT-ORDERED: 16B chunk c of each tile buffer holds
// A(row = 16*(c>>6) + (c&15), k = k0 + ((c>>4)&3)*8) — i.e. exactly the
// MFMA fragment lane (c&63) of 16-row subtile (c>>6) wants. K-loop
// ds_read_b128 is then subtile_base + lane*16: linear, conflict-free.
// (global_load_lds writes linearly; the permutation is applied on the
// per-lane GLOBAL source address — same 16-row x 64B footprint per wave,
// so VMEM coalescing is unchanged.)
template<int BN, int EPI>
__global__ __launch_bounds__(256)
void gemm_bt(const u16* __restrict__ A, const u16* __restrict__ Bt,
             u16* __restrict__ C, const u16* __restrict__ bias,
             const u16* __restrict__ res,
             u16* __restrict__ qb, u16* __restrict__ kb, u16* __restrict__ vb,
             int M, int N, int K, int lda, int ldb, int ldc,
             long sA, long sB, long sC,
             const int* __restrict__ oflag, void* __restrict__ oout)
{
    constexpr int BM = 128, BK = 32;
    constexpr int WROWS = (BN == 128) ? 2 : 4;
    constexpr int WCOLS = (BN == 128) ? 2 : 1;
    constexpr int WM = BM / WROWS, WN = BN / WCOLS;
    constexpr int MI = WM / 16, NJ = WN / 16;
    constexpr int BCH = BN * BK / 8 / 256;
    constexpr int SHSZ = 2 * BM * BK + 2 * BN * BK;   // u16 units

    __shared__ alignas(16) u16 shmem[SHSZ];
    u16* AshB = shmem;                 // 2 × BM*BK
    u16* BshB = shmem + 2 * BM * BK;   // 2 × BN*BK
    u16* Csh  = shmem;                 // EPI==1 epilogue reuse (16384 u16)

    const int tid = threadIdx.x;
    int tn = blockIdx.x, tm = blockIdx.y;
    const int bz = blockIdx.z;
    if (EPI == 4 && tn > tm) return;

    // XCD-aware swizzle (A-panel locality); requires gridDim.y % 8 == 0
    if (EPI == 1 || EPI == 2 || EPI == 3 || EPI == 6 || EPI == 7) {
        int L = blockIdx.y * gridDim.x + blockIdx.x;
        int xcd = L & 7, idx = L >> 3;
        tn = idx % gridDim.x;
        tm = (idx / gridDim.x) * 8 + xcd;
    }

    const u16* Ab = A + (long)bz * sA;
    const u16* Bb = Bt + (long)bz * sB;

    const int m0 = tm * BM, n0 = tn * BN;
    const int kEff = (EPI == 5) ? (((tm + 1) * BM < K) ? (tm + 1) * BM : K) : K;

    const int w = tid >> 6, lane = tid & 63;
    const int wrow = w % WROWS, wcol = w / WROWS;
    const int mw = wrow * WM, nw = wcol * WN;
    const int lr = lane & 15, quad = lane >> 4;

    const int ca0 = tid, ca1 = 256 + tid;
    const int cb1 = 256 + tid;

    // fragment-ordered staging addresses: chunk c -> row 16*(c>>6)+(c&15),
    // k-chunk (c>>4)&3
    const int arf0 = ((ca0 >> 6) << 4) + (ca0 & 15), acf0 = ((ca0 >> 4) & 3) * 8;
    const int arf1 = ((ca1 >> 6) << 4) + (ca1 & 15), acf1 = ((ca1 >> 4) & 3) * 8;
    const int brf0 = ((tid >> 6) << 4) + (tid & 15), bcf0 = ((tid >> 4) & 3) * 8;
    const int brf1 = ((cb1 >> 6) << 4) + (cb1 & 15), bcf1 = ((cb1 >> 4) & 3) * 8;

    auto stage = [&](int buf, int k0) {
        async16(Ab + (long)(m0 + arf0) * lda + k0 + acf0, &AshB[buf * BM * BK + ca0 * 8]);
        async16(Ab + (long)(m0 + arf1) * lda + k0 + acf1, &AshB[buf * BM * BK + ca1 * 8]);
        async16(Bb + (long)(n0 + brf0) * ldb + k0 + bcf0, &BshB[buf * BN * BK + tid * 8]);
        if (BCH == 2)
            async16(Bb + (long)(n0 + brf1) * ldb + k0 + bcf1, &BshB[buf * BN * BK + cb1 * 8]);
    };

    f32x4 acc[MI][NJ] = {};

    const int fb = lane * 8;           // u16 offset within 512-u16 subtile

    stage(0, 0);
    int cur = 0;
    for (int k0 = 0; k0 < kEff; k0 += BK) {
        __syncthreads();
        if (k0 + BK < kEff) stage(cur ^ 1, k0 + BK);

        s16x8 af[MI], bfr[NJ];
        #pragma unroll
        for (int i = 0; i < MI; i++)
            af[i] = *(const s16x8*)&AshB[cur * BM * BK + (wrow * MI + i) * 512 + fb];
        #pragma unroll
        for (int j = 0; j < NJ; j++)
            bfr[j] = *(const s16x8*)&BshB[cur * BN * BK + (wcol * NJ + j) * 512 + fb];
        #pragma unroll
        for (int i = 0; i < MI; i++)
            #pragma unroll
            for (int j = 0; j < NJ; j++)
                acc[i][j] = __builtin_amdgcn_mfma_f32_16x16x32_bf16(af[i], bfr[j], acc[i][j], 0, 0, 0);
        cur ^= 1;
    }

    if (EPI == 1) {
        const int sel = n0 >> 10;      // 0=q 1=k 2=v (tile within one section)
        const int b = m0 >> 10, sbase = m0 & 1023;
        if (sel < 2) {
            u16* dst = (sel == 0) ? qb : kb;
            #pragma unroll
            for (int i = 0; i < MI; i++)
                #pragma unroll
                for (int j = 0; j < NJ; j++)
                    #pragma unroll
                    for (int r = 0; r < 4; r++) {
                        int gm = m0 + mw + i * 16 + quad * 4 + r;
                        int gn = n0 + nw + j * 16 + lr;
                        float v = acc[i][j][r] + b2f(bias[gn]);
                        int s = gm & 1023, nn = gn & 1023, hh = nn >> 6, d = nn & 63;
                        dst[(((long)(b * 16 + hh) * 1024 + s) << 6) + d] = f2b(v);
                    }
        } else {
            // v: transpose via XOR-swizzled LDS, then coalesced d-row stores
            __syncthreads();           // all waves done reading A/B staging
            #pragma unroll
            for (int i = 0; i < MI; i++)
                #pragma unroll
                for (int j = 0; j < NJ; j++)
                    #pragma unroll
                    for (int r = 0; r < 4; r++) {
                        int nl = nw + j * 16 + lr;
                        int ml = mw + i * 16 + quad * 4 + r;
                        float v = acc[i][j][r] + b2f(bias[n0 + nl]);
                        Csh[nl * 128 + (((ml >> 3) ^ (nl & 15)) << 3) + (ml & 7)] = f2b(v);
                    }
            __syncthreads();
            const int nv0 = n0 - 2048;
            #pragma unroll
            for (int rep = 0; rep < 8; rep++) {
                int dd = rep * 16 + (tid >> 4);
                int sl = (tid & 15) * 8;
                int dg = nv0 + dd, hh = dg >> 6, dcol = dg & 63;
                u16x8 val = *(const u16x8*)&Csh[dd * 128 + ((((sl >> 3)) ^ (dd & 15)) << 3)];
                *(u16x8*)&vb[(((long)(b * 16 + hh) * 64 + dcol) << 10) + sbase + sl] = val;
            }
        }
        return;
    }

    u16* Cb;
    if (EPI == 5) Cb = C + (long)(bz >> 4) * (1 << 20) + (bz & 15) * 64;
    else          Cb = C + (long)bz * sC;

    #pragma unroll
    for (int i = 0; i < MI; i++) {
        #pragma unroll
        for (int j = 0; j < NJ; j++) {
            #pragma unroll
            for (int r = 0; r < 4; r++) {
                int gm = m0 + mw + i * 16 + quad * 4 + r;
                int gn = n0 + nw + j * 16 + lr;
                float v = acc[i][j][r];
                if (EPI == 5) {
                    Cb[(long)gm * ldc + gn] = f2b(v);
                } else if (EPI == 2) {
                    v += b2f(bias[gn]) + b2f(res[(long)gm * ldc + gn]);
                    Cb[(long)gm * ldc + gn] = f2b(v);
                } else if (EPI == 3) {
                    Cb[(long)gm * ldc + gn] = f2b(gelu_f(v + b2f(bias[gn])));
                } else if (EPI == 4) {
                    if (gn <= gm) Cb[(long)gm * ldc + gn] = f2b(v * 0.125f);
                } else if (EPI == 6) {
                    v += b2f(bias[gn]) + b2f(res[(long)gm * ldc + gn]);
                    long idx = (long)gm * ldc + gn;
                    if (*oflag) ((float*)oout)[idx] = v;
                    else        ((u16*)oout)[idx]   = f2b(v);
                } else if (EPI == 7) {
                    ((float*)oout)[(long)bz * sC + (long)gm * ldc + gn] = v;
                }
            }
        }
    }
}

extern "C" void kernel_launch(void* const* d_in, const int* in_sizes, int n_in,
                              void* d_out, int out_size, void* d_ws, size_t ws_size,
                              hipStream_t stream)
{
    const long MEG = 1L << 20;
    const long KI  = 1024;

    u16* ws = (u16*)d_ws;
    u16* xc    = ws;                    // 4Mi: bf16 x, becomes x2 in-place
    u16* winC  = ws + 4  * MEG;         // 3Mi
    u16* woutC = ws + 7  * MEG;         // 1Mi
    u16* wfcC  = ws + 8  * MEG;         // 4Mi
    u16* wprjC = ws + 12 * MEG;         // 4Mi
    u16* sm    = ws + 16 * MEG;
    u16* ln1g = sm + 0*4*KI, *ln1b = sm + 1*4*KI;
    u16* ln2g = sm + 2*4*KI, *ln2b = sm + 3*4*KI;
    u16* binC = sm + 4*4*KI;
    u16* boutC= sm + 5*4*KI;
    u16* bfcC = sm + 6*4*KI;
    u16* bprjC= sm + 7*4*KI;
    int* flag = (int*)(sm + 8*4*KI);
    u16* slotA = ws + 16 * MEG + 64 * KI;   // 4Mi: h / att / h2
    u16* qB    = slotA + 4  * MEG;
    u16* kB    = slotA + 8  * MEG;
    u16* vT    = slotA + 12 * MEG;
    u16* probs = slotA + 16 * MEG;      // chunk*(H,S,S); [0,16Mi) reused as act
    float* part = (float*)(probs + 16 * MEG);  // split-K partials (chunk=4 only)

    const long fixed_elems = 32 * MEG + 64 * KI;
    const long avail = (long)(ws_size / 2);
    int chunk = 1;
    if      (avail >= fixed_elems + 64 * MEG) chunk = 4;
    else if (avail >= fixed_elems + 32 * MEG) chunk = 2;
    const bool splitk = (chunk == 4);

    hipMemsetAsync((void*)flag, 0, sizeof(int), stream);
    detect_k<<<32, 256, 0, stream>>>((const u16*)d_in[0], flag);
    conv_w_k<<<12288, 256, 0, stream>>>(d_in[6], d_in[8], d_in[10], d_in[12],
                                        winC, flag);
    conv_small_k<<<52, 256, 0, stream>>>(d_in[2], d_in[3], d_in[4], d_in[5],
                                         d_in[7], d_in[9], d_in[11], d_in[13],
                                         sm, flag);

    u16* h   = slotA;
    u16* att = slotA;
    u16* h2  = slotA;
    u16* act = probs;

    // 1. LN1 (+x conversion)
    ln1x_k<<<4096, 256, 0, stream>>>(d_in[0], ln1g, ln1b, xc, h, flag);
    // 2. QKV projection
    gemm_bt<128, 1><<<dim3(24, 32, 1), 256, 0, stream>>>(
        h, winC, nullptr, binC, nullptr, qB, kB, vT,
        4096, 3072, 1024, 1024, 1024, 0, 0, 0, 0, nullptr, nullptr);
    // 3-6. attention
    for (int b0 = 0; b0 < 4; b0 += chunk) {
        gemm_bt<128, 4><<<dim3(8, 8, 16 * chunk), 256, 0, stream>>>(
            qB + b0 * MEG, kB + b0 * MEG, probs, nullptr, nullptr,
            nullptr, nullptr, nullptr,
            1024, 1024, 64, 64, 64, 1024, 65536, 65536, 1048576, nullptr, nullptr);
        smmean_k<<<1024 * chunk, 1024, 0, stream>>>(probs, d_out,
                                                    4 * MEG + b0 * MEG, flag);
        gemm_bt<64, 5><<<dim3(1, 8, 16 * chunk), 256, 0, stream>>>(
            probs, vT + b0 * MEG, att + b0 * MEG, nullptr, nullptr,
            nullptr, nullptr, nullptr,
            1024, 64, 1024, 1024, 1024, 1024, 1048576, 65536, 0, nullptr, nullptr);
    }
    // 7+8. x2 = x + att @ w_out^T + b_out; h2 = LN2(x2)
    if (splitk) {
        gemm_bt<128, 7><<<dim3(8, 32, 2), 256, 0, stream>>>(
            att, woutC, nullptr, nullptr, nullptr, nullptr, nullptr, nullptr,
            4096, 1024, 512, 1024, 1024, 1024, 512, 512, 4 * MEG, nullptr, part);
        redln_k<<<4096, 256, 0, stream>>>(part, 4 * MEG, boutC, xc, ln2g, ln2b, h2);
    } else {
        gemm_bt<128, 2><<<dim3(8, 32, 1), 256, 0, stream>>>(
            att, woutC, xc, boutC, xc, nullptr, nullptr, nullptr,
            4096, 1024, 1024, 1024, 1024, 1024, 0, 0, 0, nullptr, nullptr);
        ln_k<<<4096, 256, 0, stream>>>(xc, ln2g, ln2b, h2);
    }
    // 9. act = gelu(h2 @ w_fc^T + b_fc)
    gemm_bt<128, 3><<<dim3(32, 32, 1), 256, 0, stream>>>(
        h2, wfcC, act, bfcC, nullptr, nullptr, nullptr, nullptr,
        4096, 4096, 1024, 1024, 1024, 4096, 0, 0, 0, nullptr, nullptr);
    // 10. out = x2 + act @ w_proj^T + b_proj
    if (splitk) {
        gemm_bt<128, 7><<<dim3(8, 32, 4), 256, 0, stream>>>(
            act, wprjC, nullptr, nullptr, nullptr, nullptr, nullptr, nullptr,
            4096, 1024, 1024, 4096, 4096, 1024, 1024, 1024, 4 * MEG, nullptr, part);
        reduce_out_k<<<4096, 256, 0, stream>>>(part, 4 * MEG, bprjC, xc, d_out, flag);
    } else {
        gemm_bt<128, 6><<<dim3(8, 32, 1), 256, 0, stream>>>(
            act, wprjC, nullptr, bprjC, xc, nullptr, nullptr, nullptr,
            4096, 1024, 4096, 4096, 4096, 1024, 0, 0, 0, flag, d_out);
    }
}

// Round 3
// 423.588 us; speedup vs baseline: 1.1905x; 1.1905x over previous
//
#include <hip/hip_runtime.h>

typedef unsigned short u16;
typedef u16   u16x4 __attribute__((ext_vector_type(4)));
typedef u16   u16x8 __attribute__((ext_vector_type(8)));
typedef short s16x8 __attribute__((ext_vector_type(8)));
typedef float f32x4 __attribute__((ext_vector_type(4)));

__device__ __forceinline__ float b2f(u16 u) {
    union { unsigned int i; float f; } v; v.i = ((unsigned int)u) << 16; return v.f;
}
__device__ __forceinline__ u16 f2b(float f) {
    union { float f; unsigned int i; } v; v.f = f;
    unsigned int r = v.i + 0x7fffu + ((v.i >> 16) & 1u);
    return (u16)(r >> 16);
}
__device__ __forceinline__ float gelu_f(float x) {
    float z = 0.7978845608028654f * (x + 0.044715f * x * x * x);
    float e = __expf(2.0f * z);
    float t = 1.0f - 2.0f / (e + 1.0f);
    return 0.5f * x * (1.0f + t);
}
__device__ __forceinline__ void async16(const u16* g, u16* l) {
    __builtin_amdgcn_global_load_lds(
        (const __attribute__((address_space(1))) unsigned int*)g,
        (__attribute__((address_space(3))) unsigned int*)l,
        16, 0, 0);
}

// ---- dtype detector: bf16-read exponent >= 2^60 anywhere => fp32 input
__global__ __launch_bounds__(256)
void detect_k(const u16* __restrict__ x, int* __restrict__ flag)
{
    int gid = blockIdx.x * 256 + threadIdx.x;
    const u16x8 u = *(const u16x8*)(x + (long)gid * 8);
    int bad = 0;
    #pragma unroll
    for (int e = 0; e < 8; e++) {
        int ex = (u[e] >> 7) & 0xFF;
        if (ex >= 187) bad = 1;
    }
    unsigned long long m = __ballot(bad != 0);
    if ((threadIdx.x & 63) == 0 && m != 0ull) atomicOr(flag, 1);
}

// ---- weight converter (vec4): w_in|w_out|w_fc|w_proj -> ws[4Mi..16Mi)
__global__ __launch_bounds__(256)
void conv_w_k(const void* __restrict__ s0, const void* __restrict__ s1,
              const void* __restrict__ s2, const void* __restrict__ s3,
              u16* __restrict__ dst, const int* __restrict__ flag)
{
    const long MEG = 1L << 20;
    long gid = ((long)blockIdx.x * 256 + threadIdx.x) * 4;   // < 12Mi
    const void* s; long off;
    if      (gid <  3*MEG) { s = s0; off = gid; }
    else if (gid <  4*MEG) { s = s1; off = gid - 3*MEG; }
    else if (gid <  8*MEG) { s = s2; off = gid - 4*MEG; }
    else                   { s = s3; off = gid - 8*MEG; }
    u16x4 o;
    if (*flag) {
        const float4 f = *(const float4*)((const float*)s + off);
        o[0] = f2b(f.x); o[1] = f2b(f.y); o[2] = f2b(f.z); o[3] = f2b(f.w);
    } else {
        o = *(const u16x4*)((const u16*)s + off);
    }
    *(u16x4*)(dst + gid) = o;
}

// ---- fused small-param converter into 4Ki-slotted region
__global__ __launch_bounds__(256)
void conv_small_k(const void* s0, const void* s1, const void* s2, const void* s3,
                  const void* s4, const void* s5, const void* s6, const void* s7,
                  u16* __restrict__ dst, const int* __restrict__ flag)
{
    int gid = blockIdx.x * 256 + threadIdx.x;          // < 13312
    int seg, off;
    if      (gid <  4096) { seg = gid >> 10;  off = gid & 1023; }
    else if (gid <  7168) { seg = 4; off = gid - 4096; }
    else if (gid <  8192) { seg = 5; off = gid - 7168; }
    else if (gid < 12288) { seg = 6; off = gid - 8192; }
    else                  { seg = 7; off = gid - 12288; }
    const void* srcs[8] = {s0, s1, s2, s3, s4, s5, s6, s7};
    const void* s = srcs[seg];
    dst[seg * 4096 + off] = (*flag) ? f2b(((const float*)s)[off]) : ((const u16*)s)[off];
}

// ---- LN1 fused with x conversion
__global__ __launch_bounds__(256)
void ln1x_k(const void* __restrict__ xraw, const u16* __restrict__ g,
            const u16* __restrict__ b, u16* __restrict__ xc,
            u16* __restrict__ o, const int* __restrict__ flag)
{
    long row = blockIdx.x;
    int tid = threadIdx.x;
    float v0, v1, v2, v3;
    if (*flag) {
        const float4 f = *(const float4*)((const float*)xraw + row * 1024 + tid * 4);
        v0 = b2f(f2b(f.x)); v1 = b2f(f2b(f.y));
        v2 = b2f(f2b(f.z)); v3 = b2f(f2b(f.w));
    } else {
        const u16x4 u = *(const u16x4*)((const u16*)xraw + row * 1024 + tid * 4);
        v0 = b2f(u[0]); v1 = b2f(u[1]); v2 = b2f(u[2]); v3 = b2f(u[3]);
    }
    u16x4 xv; xv[0] = f2b(v0); xv[1] = f2b(v1); xv[2] = f2b(v2); xv[3] = f2b(v3);
    *(u16x4*)(xc + row * 1024 + tid * 4) = xv;
    float s  = v0 + v1 + v2 + v3;
    float sq = v0*v0 + v1*v1 + v2*v2 + v3*v3;
    #pragma unroll
    for (int off = 32; off; off >>= 1) { s += __shfl_xor(s, off); sq += __shfl_xor(sq, off); }
    __shared__ float sm[8];
    int wid = tid >> 6, lane = tid & 63;
    if (lane == 0) { sm[wid] = s; sm[wid + 4] = sq; }
    __syncthreads();
    s  = sm[0] + sm[1] + sm[2] + sm[3];
    sq = sm[4] + sm[5] + sm[6] + sm[7];
    float mean = s * (1.0f / 1024.0f);
    float var  = sq * (1.0f / 1024.0f) - mean * mean;
    float rs   = rsqrtf(var + 1e-5f);
    u16x4 gg = *(const u16x4*)(g + tid * 4);
    u16x4 bb = *(const u16x4*)(b + tid * 4);
    u16x4 ov;
    ov[0] = f2b((v0 - mean) * rs * b2f(gg[0]) + b2f(bb[0]));
    ov[1] = f2b((v1 - mean) * rs * b2f(gg[1]) + b2f(bb[1]));
    ov[2] = f2b((v2 - mean) * rs * b2f(gg[2]) + b2f(bb[2]));
    ov[3] = f2b((v3 - mean) * rs * b2f(gg[3]) + b2f(bb[3]));
    *(u16x4*)(o + row * 1024 + tid * 4) = ov;
}

// ---- plain LN (fallback path)
__global__ __launch_bounds__(256)
void ln_k(const u16* __restrict__ x, const u16* __restrict__ g,
          const u16* __restrict__ b, u16* __restrict__ o)
{
    long row = blockIdx.x;
    int tid = threadIdx.x;
    const u16x4 u = *(const u16x4*)(x + row * 1024 + tid * 4);
    float v0 = b2f(u[0]), v1 = b2f(u[1]), v2 = b2f(u[2]), v3 = b2f(u[3]);
    float s  = v0 + v1 + v2 + v3;
    float sq = v0*v0 + v1*v1 + v2*v2 + v3*v3;
    #pragma unroll
    for (int off = 32; off; off >>= 1) { s += __shfl_xor(s, off); sq += __shfl_xor(sq, off); }
    __shared__ float sm[8];
    int wid = tid >> 6, lane = tid & 63;
    if (lane == 0) { sm[wid] = s; sm[wid + 4] = sq; }
    __syncthreads();
    s  = sm[0] + sm[1] + sm[2] + sm[3];
    sq = sm[4] + sm[5] + sm[6] + sm[7];
    float mean = s * (1.0f / 1024.0f);
    float var  = sq * (1.0f / 1024.0f) - mean * mean;
    float rs   = rsqrtf(var + 1e-5f);
    u16x4 gg = *(const u16x4*)(g + tid * 4);
    u16x4 bb = *(const u16x4*)(b + tid * 4);
    u16x4 ov;
    ov[0] = f2b((v0 - mean) * rs * b2f(gg[0]) + b2f(bb[0]));
    ov[1] = f2b((v1 - mean) * rs * b2f(gg[1]) + b2f(bb[1]));
    ov[2] = f2b((v2 - mean) * rs * b2f(gg[2]) + b2f(bb[2]));
    ov[3] = f2b((v3 - mean) * rs * b2f(gg[3]) + b2f(bb[3]));
    *(u16x4*)(o + row * 1024 + tid * 4) = ov;
}

// ---- fused split-K(2) reduce + LN2
__global__ __launch_bounds__(256)
void redln_k(const float* __restrict__ P, long slice,
             const u16* __restrict__ bias, u16* __restrict__ res,
             const u16* __restrict__ g, const u16* __restrict__ b,
             u16* __restrict__ o)
{
    long row = blockIdx.x;
    int tid = threadIdx.x;
    long i = row * 1024 + tid * 4;
    float4 v  = *(const float4*)(P + i);
    float4 p1 = *(const float4*)(P + slice + i);
    u16x4 bb = *(const u16x4*)(bias + tid * 4);
    u16x4 rr = *(const u16x4*)(res + i);
    float v0 = b2f(f2b(v.x + p1.x + b2f(bb[0]) + b2f(rr[0])));
    float v1 = b2f(f2b(v.y + p1.y + b2f(bb[1]) + b2f(rr[1])));
    float v2 = b2f(f2b(v.z + p1.z + b2f(bb[2]) + b2f(rr[2])));
    float v3 = b2f(f2b(v.w + p1.w + b2f(bb[3]) + b2f(rr[3])));
    u16x4 xv; xv[0] = f2b(v0); xv[1] = f2b(v1); xv[2] = f2b(v2); xv[3] = f2b(v3);
    *(u16x4*)(res + i) = xv;
    float s  = v0 + v1 + v2 + v3;
    float sq = v0*v0 + v1*v1 + v2*v2 + v3*v3;
    #pragma unroll
    for (int off = 32; off; off >>= 1) { s += __shfl_xor(s, off); sq += __shfl_xor(sq, off); }
    __shared__ float sm[8];
    int wid = tid >> 6, lane = tid & 63;
    if (lane == 0) { sm[wid] = s; sm[wid + 4] = sq; }
    __syncthreads();
    s  = sm[0] + sm[1] + sm[2] + sm[3];
    sq = sm[4] + sm[5] + sm[6] + sm[7];
    float mean = s * (1.0f / 1024.0f);
    float var  = sq * (1.0f / 1024.0f) - mean * mean;
    float rs   = rsqrtf(var + 1e-5f);
    u16x4 gg = *(const u16x4*)(g + tid * 4);
    u16x4 b2 = *(const u16x4*)(b + tid * 4);
    u16x4 ov;
    ov[0] = f2b((v0 - mean) * rs * b2f(gg[0]) + b2f(b2[0]));
    ov[1] = f2b((v1 - mean) * rs * b2f(gg[1]) + b2f(b2[1]));
    ov[2] = f2b((v2 - mean) * rs * b2f(gg[2]) + b2f(b2[2]));
    ov[3] = f2b((v3 - mean) * rs * b2f(gg[3]) + b2f(b2[3]));
    *(u16x4*)(o + row * 1024 + tid * 4) = ov;
}

// -------- Fused softmax (causal, in-place) + mean-over-heads ----------
__global__ __launch_bounds__(1024)
void smmean_k(u16* __restrict__ probs, void* __restrict__ ow, long ofs,
              const int* __restrict__ flag)
{
    const long MEG = 1L << 20;
    __shared__ float red[16 * 1024];
    int bl = blockIdx.x >> 10;           // batch within chunk
    int q  = blockIdx.x & 1023;
    int w = threadIdx.x >> 6, lane = threadIdx.x & 63;
    int tile_end = ((q >> 7) + 1) << 7;
    u16* row = probs + (((long)(bl * 16 + w)) << 20) + (long)q * 1024;
    float v[16];
    float m = -3.0e38f;
    #pragma unroll
    for (int c = 0; c < 2; c++) {
        int kb = (c * 64 + lane) * 8;
        if (kb <= q) {
            u16x8 u = *(const u16x8*)(row + kb);
            #pragma unroll
            for (int e = 0; e < 8; e++) {
                if (kb + e <= q) {
                    float f = b2f(u[e]);
                    v[c * 8 + e] = f;
                    m = fmaxf(m, f);
                } else v[c * 8 + e] = -3.0e38f;
            }
        } else {
            #pragma unroll
            for (int e = 0; e < 8; e++) v[c * 8 + e] = -3.0e38f;
        }
    }
    #pragma unroll
    for (int off = 32; off; off >>= 1) m = fmaxf(m, __shfl_xor(m, off));
    float s = 0.0f;
    #pragma unroll
    for (int t = 0; t < 16; t++) {
        float e = (v[t] > -1.0e38f) ? __expf(v[t] - m) : 0.0f;
        v[t] = e; s += e;
    }
    #pragma unroll
    for (int off = 32; off; off >>= 1) s += __shfl_xor(s, off);
    float inv = 1.0f / s;
    #pragma unroll
    for (int c = 0; c < 2; c++) {
        int kb = (c * 64 + lane) * 8;
        float p[8];
        #pragma unroll
        for (int e = 0; e < 8; e++) p[e] = v[c * 8 + e] * inv;
        #pragma unroll
        for (int e = 0; e < 8; e++) red[w * 1024 + kb + e] = p[e];
        if (kb < tile_end) {
            u16x8 o;
            #pragma unroll
            for (int e = 0; e < 8; e++) o[e] = f2b(p[e]);
            *(u16x8*)(row + kb) = o;
        }
    }
    __syncthreads();
    int t = threadIdx.x;
    float acc = 0.0f;
    #pragma unroll
    for (int h = 0; h < 16; h++) acc += red[h * 1024 + t];
    acc *= 0.0625f;
    long idx = ofs + (long)bl * MEG + (long)q * 1024 + t;
    if (*flag) ((float*)ow)[idx] = acc;
    else       ((u16*)ow)[idx]   = f2b(acc);
}

// -------- split-K(4) reduce for final output --------
__global__ __launch_bounds__(256)
void reduce_out_k(const float* __restrict__ P, long slice,
                  const u16* __restrict__ bias, const u16* __restrict__ res,
                  void* __restrict__ out, const int* __restrict__ flag)
{
    long i = ((long)blockIdx.x * 256 + threadIdx.x) * 4;
    int gn = (int)(i & 1023);
    float4 v = *(const float4*)(P + i);
    #pragma unroll
    for (int s = 1; s < 4; s++) {
        const float4 p = *(const float4*)(P + (long)s * slice + i);
        v.x += p.x; v.y += p.y; v.z += p.z; v.w += p.w;
    }
    u16x4 bb = *(const u16x4*)(bias + gn);
    u16x4 rr = *(const u16x4*)(res + i);
    v.x += b2f(bb[0]) + b2f(rr[0]);
    v.y += b2f(bb[1]) + b2f(rr[1]);
    v.z += b2f(bb[2]) + b2f(rr[2]);
    v.w += b2f(bb[3]) + b2f(rr[3]);
    if (*flag) {
        *(float4*)((float*)out + i) = v;
    } else {
        u16x4 o;
        o[0] = f2b(v.x); o[1] = f2b(v.y); o[2] = f2b(v.z); o[3] = f2b(v.w);
        *(u16x4*)((u16*)out + i) = o;
    }
}

// ---------------- gemm_bt: C[m,n] = sum_k A[m,k]*Bt[n,k] + epilogue ---
// EPI: 1 qkv-routing (+bias, v via LDS transpose), 2 +bias+residual,
//      3 gelu(+bias), 4 scores (scale+causal), 5 PV (k-limit),
//      6 +bias+residual flag-adaptive, 7 split-K fp32 partial
//
// LDS tile is row-major [rows][BK=32 u16] with an IN-ROW XOR swizzle:
// the 16B k-chunk s of row r sits at slot position s ^ ((r>>1)&3).
// Applied both-sides: staging permutes the per-lane GLOBAL column within
// the same 64B row-segment (4-lane groups keep full line locality ->
// coalescing preserved), and the fragment ds_read_b128 XORs its quad with
// ((lr>>1)&3). Effect: every consecutive-8-lane LDS phase covers all 8
// 16B bank positions -> zero bank conflicts without R2's VMEM scatter.
template<int BN, int EPI>
__global__ __launch_bounds__(256)
void gemm_bt(const u16* __restrict__ A, const u16* __restrict__ Bt,
             u16* __restrict__ C, const u16* __restrict__ bias,
             const u16* __restrict__ res,
             u16* __restrict__ qb, u16* __restrict__ kb, u16* __restrict__ vb,
             int M, int N, int K, int lda, int ldb, int ldc,
             long sA, long sB, long sC,
             const int* __restrict__ oflag, void* __restrict__ oout)
{
    constexpr int BM = 128, BK = 32;
    constexpr int WROWS = (BN == 128) ? 2 : 4;
    constexpr int WCOLS = (BN == 128) ? 2 : 1;
    constexpr int WM = BM / WROWS, WN = BN / WCOLS;
    constexpr int MI = WM / 16, NJ = WN / 16;
    constexpr int BCH = BN * BK / 8 / 256;
    constexpr int SHSZ = 2 * BM * BK + 2 * BN * BK;   // u16 units

    __shared__ alignas(16) u16 shmem[SHSZ];
    u16* AshB = shmem;                 // 2 × BM*BK
    u16* BshB = shmem + 2 * BM * BK;   // 2 × BN*BK
    u16* Csh  = shmem;                 // EPI==1 epilogue reuse (16384 u16)

    const int tid = threadIdx.x;
    int tn = blockIdx.x, tm = blockIdx.y;
    const int bz = blockIdx.z;
    if (EPI == 4 && tn > tm) return;

    // XCD-aware swizzle (A-panel locality); requires gridDim.y % 8 == 0
    if (EPI == 1 || EPI == 2 || EPI == 3 || EPI == 6 || EPI == 7) {
        int L = blockIdx.y * gridDim.x + blockIdx.x;
        int xcd = L & 7, idx = L >> 3;
        tn = idx % gridDim.x;
        tm = (idx / gridDim.x) * 8 + xcd;
    }

    const u16* Ab = A + (long)bz * sA;
    const u16* Bb = Bt + (long)bz * sB;

    const int m0 = tm * BM, n0 = tn * BN;
    const int kEff = (EPI == 5) ? (((tm + 1) * BM < K) ? (tm + 1) * BM : K) : K;

    const int w = tid >> 6, lane = tid & 63;
    const int wrow = w % WROWS, wcol = w / WROWS;
    const int mw = wrow * WM, nw = wcol * WN;
    const int lr = lane & 15, quad = lane >> 4;

    const int ca0 = tid, ca1 = 256 + tid;
    const int cb1 = 256 + tid;

    // staging: chunk c -> row c>>2; global k-chunk = (c&3) ^ ((c>>3)&3)
    // (inverse of the read-side swizzle; stays within the same 64B row)
    const int ar0 = ca0 >> 2, ac0 = (((ca0 & 3) ^ ((ca0 >> 3) & 3))) * 8;
    const int ar1 = ca1 >> 2, ac1 = (((ca1 & 3) ^ ((ca1 >> 3) & 3))) * 8;
    const int br0 = tid >> 2, bc0 = (((tid & 3) ^ ((tid >> 3) & 3))) * 8;
    const int br1 = cb1 >> 2, bc1 = (((cb1 & 3) ^ ((cb1 >> 3) & 3))) * 8;

    auto stage = [&](int buf, int k0) {
        async16(Ab + (long)(m0 + ar0) * lda + k0 + ac0, &AshB[buf * BM * BK + ca0 * 8]);
        async16(Ab + (long)(m0 + ar1) * lda + k0 + ac1, &AshB[buf * BM * BK + ca1 * 8]);
        async16(Bb + (long)(n0 + br0) * ldb + k0 + bc0, &BshB[buf * BN * BK + tid * 8]);
        if (BCH == 2)
            async16(Bb + (long)(n0 + br1) * ldb + k0 + bc1, &BshB[buf * BN * BK + cb1 * 8]);
    };

    f32x4 acc[MI][NJ] = {};

    // fragment read offset: quad XOR'd with ((lr>>1)&3) (row-dependent part
    // of the swizzle; mw + i*16 is a multiple of 16 so only lr matters)
    const int foff = (quad ^ ((lr >> 1) & 3)) * 8;

    stage(0, 0);
    int cur = 0;
    for (int k0 = 0; k0 < kEff; k0 += BK) {
        __syncthreads();
        if (k0 + BK < kEff) stage(cur ^ 1, k0 + BK);

        s16x8 af[MI], bfr[NJ];
        #pragma unroll
        for (int i = 0; i < MI; i++)
            af[i] = *(const s16x8*)&AshB[cur * BM * BK + (mw + i * 16 + lr) * BK + foff];
        #pragma unroll
        for (int j = 0; j < NJ; j++)
            bfr[j] = *(const s16x8*)&BshB[cur * BN * BK + (nw + j * 16 + lr) * BK + foff];
        #pragma unroll
        for (int i = 0; i < MI; i++)
            #pragma unroll
            for (int j = 0; j < NJ; j++)
                acc[i][j] = __builtin_amdgcn_mfma_f32_16x16x32_bf16(af[i], bfr[j], acc[i][j], 0, 0, 0);
        cur ^= 1;
    }

    if (EPI == 1) {
        const int sel = n0 >> 10;      // 0=q 1=k 2=v (tile within one section)
        const int b = m0 >> 10, sbase = m0 & 1023;
        if (sel < 2) {
            u16* dst = (sel == 0) ? qb : kb;
            #pragma unroll
            for (int i = 0; i < MI; i++)
                #pragma unroll
                for (int j = 0; j < NJ; j++)
                    #pragma unroll
                    for (int r = 0; r < 4; r++) {
                        int gm = m0 + mw + i * 16 + quad * 4 + r;
                        int gn = n0 + nw + j * 16 + lr;
                        float v = acc[i][j][r] + b2f(bias[gn]);
                        int s = gm & 1023, nn = gn & 1023, hh = nn >> 6, d = nn & 63;
                        dst[(((long)(b * 16 + hh) * 1024 + s) << 6) + d] = f2b(v);
                    }
        } else {
            // v: transpose via XOR-swizzled LDS, then coalesced d-row stores
            __syncthreads();           // all waves done reading A/B staging
            #pragma unroll
            for (int i = 0; i < MI; i++)
                #pragma unroll
                for (int j = 0; j < NJ; j++)
                    #pragma unroll
                    for (int r = 0; r < 4; r++) {
                        int nl = nw + j * 16 + lr;
                        int ml = mw + i * 16 + quad * 4 + r;
                        float v = acc[i][j][r] + b2f(bias[n0 + nl]);
                        Csh[nl * 128 + (((ml >> 3) ^ (nl & 15)) << 3) + (ml & 7)] = f2b(v);
                    }
            __syncthreads();
            const int nv0 = n0 - 2048;
            #pragma unroll
            for (int rep = 0; rep < 8; rep++) {
                int dd = rep * 16 + (tid >> 4);
                int sl = (tid & 15) * 8;
                int dg = nv0 + dd, hh = dg >> 6, dcol = dg & 63;
                u16x8 val = *(const u16x8*)&Csh[dd * 128 + ((((sl >> 3)) ^ (dd & 15)) << 3)];
                *(u16x8*)&vb[(((long)(b * 16 + hh) * 64 + dcol) << 10) + sbase + sl] = val;
            }
        }
        return;
    }

    u16* Cb;
    if (EPI == 5) Cb = C + (long)(bz >> 4) * (1 << 20) + (bz & 15) * 64;
    else          Cb = C + (long)bz * sC;

    #pragma unroll
    for (int i = 0; i < MI; i++) {
        #pragma unroll
        for (int j = 0; j < NJ; j++) {
            #pragma unroll
            for (int r = 0; r < 4; r++) {
                int gm = m0 + mw + i * 16 + quad * 4 + r;
                int gn = n0 + nw + j * 16 + lr;
                float v = acc[i][j][r];
                if (EPI == 5) {
                    Cb[(long)gm * ldc + gn] = f2b(v);
                } else if (EPI == 2) {
                    v += b2f(bias[gn]) + b2f(res[(long)gm * ldc + gn]);
                    Cb[(long)gm * ldc + gn] = f2b(v);
                } else if (EPI == 3) {
                    Cb[(long)gm * ldc + gn] = f2b(gelu_f(v + b2f(bias[gn])));
                } else if (EPI == 4) {
                    if (gn <= gm) Cb[(long)gm * ldc + gn] = f2b(v * 0.125f);
                } else if (EPI == 6) {
                    v += b2f(bias[gn]) + b2f(res[(long)gm * ldc + gn]);
                    long idx = (long)gm * ldc + gn;
                    if (*oflag) ((float*)oout)[idx] = v;
                    else        ((u16*)oout)[idx]   = f2b(v);
                } else if (EPI == 7) {
                    ((float*)oout)[(long)bz * sC + (long)gm * ldc + gn] = v;
                }
            }
        }
    }
}

extern "C" void kernel_launch(void* const* d_in, const int* in_sizes, int n_in,
                              void* d_out, int out_size, void* d_ws, size_t ws_size,
                              hipStream_t stream)
{
    const long MEG = 1L << 20;
    const long KI  = 1024;

    u16* ws = (u16*)d_ws;
    u16* xc    = ws;                    // 4Mi: bf16 x, becomes x2 in-place
    u16* winC  = ws + 4  * MEG;         // 3Mi
    u16* woutC = ws + 7  * MEG;         // 1Mi
    u16* wfcC  = ws + 8  * MEG;         // 4Mi
    u16* wprjC = ws + 12 * MEG;         // 4Mi
    u16* sm    = ws + 16 * MEG;
    u16* ln1g = sm + 0*4*KI, *ln1b = sm + 1*4*KI;
    u16* ln2g = sm + 2*4*KI, *ln2b = sm + 3*4*KI;
    u16* binC = sm + 4*4*KI;
    u16* boutC= sm + 5*4*KI;
    u16* bfcC = sm + 6*4*KI;
    u16* bprjC= sm + 7*4*KI;
    int* flag = (int*)(sm + 8*4*KI);
    u16* slotA = ws + 16 * MEG + 64 * KI;   // 4Mi: h / att / h2
    u16* qB    = slotA + 4  * MEG;
    u16* kB    = slotA + 8  * MEG;
    u16* vT    = slotA + 12 * MEG;
    u16* probs = slotA + 16 * MEG;      // chunk*(H,S,S); [0,16Mi) reused as act
    float* part = (float*)(probs + 16 * MEG);  // split-K partials (chunk=4 only)

    const long fixed_elems = 32 * MEG + 64 * KI;
    const long avail = (long)(ws_size / 2);
    int chunk = 1;
    if      (avail >= fixed_elems + 64 * MEG) chunk = 4;
    else if (avail >= fixed_elems + 32 * MEG) chunk = 2;
    const bool splitk = (chunk == 4);

    hipMemsetAsync((void*)flag, 0, sizeof(int), stream);
    detect_k<<<32, 256, 0, stream>>>((const u16*)d_in[0], flag);
    conv_w_k<<<12288, 256, 0, stream>>>(d_in[6], d_in[8], d_in[10], d_in[12],
                                        winC, flag);
    conv_small_k<<<52, 256, 0, stream>>>(d_in[2], d_in[3], d_in[4], d_in[5],
                                         d_in[7], d_in[9], d_in[11], d_in[13],
                                         sm, flag);

    u16* h   = slotA;
    u16* att = slotA;
    u16* h2  = slotA;
    u16* act = probs;

    // 1. LN1 (+x conversion)
    ln1x_k<<<4096, 256, 0, stream>>>(d_in[0], ln1g, ln1b, xc, h, flag);
    // 2. QKV projection
    gemm_bt<128, 1><<<dim3(24, 32, 1), 256, 0, stream>>>(
        h, winC, nullptr, binC, nullptr, qB, kB, vT,
        4096, 3072, 1024, 1024, 1024, 0, 0, 0, 0, nullptr, nullptr);
    // 3-6. attention
    for (int b0 = 0; b0 < 4; b0 += chunk) {
        gemm_bt<128, 4><<<dim3(8, 8, 16 * chunk), 256, 0, stream>>>(
            qB + b0 * MEG, kB + b0 * MEG, probs, nullptr, nullptr,
            nullptr, nullptr, nullptr,
            1024, 1024, 64, 64, 64, 1024, 65536, 65536, 1048576, nullptr, nullptr);
        smmean_k<<<1024 * chunk, 1024, 0, stream>>>(probs, d_out,
                                                    4 * MEG + b0 * MEG, flag);
        gemm_bt<64, 5><<<dim3(1, 8, 16 * chunk), 256, 0, stream>>>(
            probs, vT + b0 * MEG, att + b0 * MEG, nullptr, nullptr,
            nullptr, nullptr, nullptr,
            1024, 64, 1024, 1024, 1024, 1024, 1048576, 65536, 0, nullptr, nullptr);
    }
    // 7+8. x2 = x + att @ w_out^T + b_out; h2 = LN2(x2)
    if (splitk) {
        gemm_bt<128, 7><<<dim3(8, 32, 2), 256, 0, stream>>>(
            att, woutC, nullptr, nullptr, nullptr, nullptr, nullptr, nullptr,
            4096, 1024, 512, 1024, 1024, 1024, 512, 512, 4 * MEG, nullptr, part);
        redln_k<<<4096, 256, 0, stream>>>(part, 4 * MEG, boutC, xc, ln2g, ln2b, h2);
    } else {
        gemm_bt<128, 2><<<dim3(8, 32, 1), 256, 0, stream>>>(
            att, woutC, xc, boutC, xc, nullptr, nullptr, nullptr,
            4096, 1024, 1024, 1024, 1024, 1024, 0, 0, 0, nullptr, nullptr);
        ln_k<<<4096, 256, 0, stream>>>(xc, ln2g, ln2b, h2);
    }
    // 9. act = gelu(h2 @ w_fc^T + b_fc)
    gemm_bt<128, 3><<<dim3(32, 32, 1), 256, 0, stream>>>(
        h2, wfcC, act, bfcC, nullptr, nullptr, nullptr, nullptr,
        4096, 4096, 1024, 1024, 1024, 4096, 0, 0, 0, nullptr, nullptr);
    // 10. out = x2 + act @ w_proj^T + b_proj
    if (splitk) {
        gemm_bt<128, 7><<<dim3(8, 32, 4), 256, 0, stream>>>(
            act, wprjC, nullptr, nullptr, nullptr, nullptr, nullptr, nullptr,
            4096, 1024, 1024, 4096, 4096, 1024, 1024, 1024, 4 * MEG, nullptr, part);
        reduce_out_k<<<4096, 256, 0, stream>>>(part, 4 * MEG, bprjC, xc, d_out, flag);
    } else {
        gemm_bt<128, 6><<<dim3(8, 32, 1), 256, 0, stream>>>(
            act, wprjC, nullptr, bprjC, xc, nullptr, nullptr, nullptr,
            4096, 1024, 4096, 4096, 4096, 1024, 0, 0, 0, flag, d_out);
    }
}

// Round 5
// 416.611 us; speedup vs baseline: 1.2104x; 1.0167x over previous
//
#include <hip/hip_runtime.h>

typedef unsigned short u16;
typedef u16   u16x4 __attribute__((ext_vector_type(4)));
typedef u16   u16x8 __attribute__((ext_vector_type(8)));
typedef short s16x8 __attribute__((ext_vector_type(8)));
typedef float f32x4 __attribute__((ext_vector_type(4)));

__device__ __forceinline__ float b2f(u16 u) {
    union { unsigned int i; float f; } v; v.i = ((unsigned int)u) << 16; return v.f;
}
__device__ __forceinline__ u16 f2b(float f) {
    union { float f; unsigned int i; } v; v.f = f;
    unsigned int r = v.i + 0x7fffu + ((v.i >> 16) & 1u);
    return (u16)(r >> 16);
}
__device__ __forceinline__ float gelu_f(float x) {
    float z = 0.7978845608028654f * (x + 0.044715f * x * x * x);
    float e = __expf(2.0f * z);
    float t = 1.0f - 2.0f / (e + 1.0f);
    return 0.5f * x * (1.0f + t);
}
__device__ __forceinline__ void async16(const u16* g, u16* l) {
    __builtin_amdgcn_global_load_lds(
        (const __attribute__((address_space(1))) unsigned int*)g,
        (__attribute__((address_space(3))) unsigned int*)l,
        16, 0, 0);
}

#define FEN() asm volatile("" ::: "memory")
#define BARR() { FEN(); __builtin_amdgcn_s_barrier(); FEN(); }
#define LGKM0() { asm volatile("s_waitcnt lgkmcnt(0)" ::: "memory"); __builtin_amdgcn_sched_barrier(0); }
#define VMC(N) asm volatile("s_waitcnt vmcnt(" #N ")" ::: "memory")

// ---- dtype detector: bf16-read exponent >= 2^60 anywhere => fp32 input
__global__ __launch_bounds__(256)
void detect_k(const u16* __restrict__ x, int* __restrict__ flag)
{
    int gid = blockIdx.x * 256 + threadIdx.x;
    const u16x8 u = *(const u16x8*)(x + (long)gid * 8);
    int bad = 0;
    #pragma unroll
    for (int e = 0; e < 8; e++) {
        int ex = (u[e] >> 7) & 0xFF;
        if (ex >= 187) bad = 1;
    }
    unsigned long long m = __ballot(bad != 0);
    if ((threadIdx.x & 63) == 0 && m != 0ull) atomicOr(flag, 1);
}

// ---- weight converter (vec4): w_in|w_out|w_fc|w_proj -> ws[4Mi..16Mi)
__global__ __launch_bounds__(256)
void conv_w_k(const void* __restrict__ s0, const void* __restrict__ s1,
              const void* __restrict__ s2, const void* __restrict__ s3,
              u16* __restrict__ dst, const int* __restrict__ flag)
{
    const long MEG = 1L << 20;
    long gid = ((long)blockIdx.x * 256 + threadIdx.x) * 4;   // < 12Mi
    const void* s; long off;
    if      (gid <  3*MEG) { s = s0; off = gid; }
    else if (gid <  4*MEG) { s = s1; off = gid - 3*MEG; }
    else if (gid <  8*MEG) { s = s2; off = gid - 4*MEG; }
    else                   { s = s3; off = gid - 8*MEG; }
    u16x4 o;
    if (*flag) {
        const float4 f = *(const float4*)((const float*)s + off);
        o[0] = f2b(f.x); o[1] = f2b(f.y); o[2] = f2b(f.z); o[3] = f2b(f.w);
    } else {
        o = *(const u16x4*)((const u16*)s + off);
    }
    *(u16x4*)(dst + gid) = o;
}

// ---- fused small-param converter into 4Ki-slotted region
__global__ __launch_bounds__(256)
void conv_small_k(const void* s0, const void* s1, const void* s2, const void* s3,
                  const void* s4, const void* s5, const void* s6, const void* s7,
                  u16* __restrict__ dst, const int* __restrict__ flag)
{
    int gid = blockIdx.x * 256 + threadIdx.x;          // < 13312
    int seg, off;
    if      (gid <  4096) { seg = gid >> 10;  off = gid & 1023; }
    else if (gid <  7168) { seg = 4; off = gid - 4096; }
    else if (gid <  8192) { seg = 5; off = gid - 7168; }
    else if (gid < 12288) { seg = 6; off = gid - 8192; }
    else                  { seg = 7; off = gid - 12288; }
    const void* srcs[8] = {s0, s1, s2, s3, s4, s5, s6, s7};
    const void* s = srcs[seg];
    dst[seg * 4096 + off] = (*flag) ? f2b(((const float*)s)[off]) : ((const u16*)s)[off];
}

// ---- LN1 fused with x conversion
__global__ __launch_bounds__(256)
void ln1x_k(const void* __restrict__ xraw, const u16* __restrict__ g,
            const u16* __restrict__ b, u16* __restrict__ xc,
            u16* __restrict__ o, const int* __restrict__ flag)
{
    long row = blockIdx.x;
    int tid = threadIdx.x;
    float v0, v1, v2, v3;
    if (*flag) {
        const float4 f = *(const float4*)((const float*)xraw + row * 1024 + tid * 4);
        v0 = b2f(f2b(f.x)); v1 = b2f(f2b(f.y));
        v2 = b2f(f2b(f.z)); v3 = b2f(f2b(f.w));
    } else {
        const u16x4 u = *(const u16x4*)((const u16*)xraw + row * 1024 + tid * 4);
        v0 = b2f(u[0]); v1 = b2f(u[1]); v2 = b2f(u[2]); v3 = b2f(u[3]);
    }
    u16x4 xv; xv[0] = f2b(v0); xv[1] = f2b(v1); xv[2] = f2b(v2); xv[3] = f2b(v3);
    *(u16x4*)(xc + row * 1024 + tid * 4) = xv;
    float s  = v0 + v1 + v2 + v3;
    float sq = v0*v0 + v1*v1 + v2*v2 + v3*v3;
    #pragma unroll
    for (int off = 32; off; off >>= 1) { s += __shfl_xor(s, off); sq += __shfl_xor(sq, off); }
    __shared__ float sm[8];
    int wid = tid >> 6, lane = tid & 63;
    if (lane == 0) { sm[wid] = s; sm[wid + 4] = sq; }
    __syncthreads();
    s  = sm[0] + sm[1] + sm[2] + sm[3];
    sq = sm[4] + sm[5] + sm[6] + sm[7];
    float mean = s * (1.0f / 1024.0f);
    float var  = sq * (1.0f / 1024.0f) - mean * mean;
    float rs   = rsqrtf(var + 1e-5f);
    u16x4 gg = *(const u16x4*)(g + tid * 4);
    u16x4 bb = *(const u16x4*)(b + tid * 4);
    u16x4 ov;
    ov[0] = f2b((v0 - mean) * rs * b2f(gg[0]) + b2f(bb[0]));
    ov[1] = f2b((v1 - mean) * rs * b2f(gg[1]) + b2f(bb[1]));
    ov[2] = f2b((v2 - mean) * rs * b2f(gg[2]) + b2f(bb[2]));
    ov[3] = f2b((v3 - mean) * rs * b2f(gg[3]) + b2f(bb[3]));
    *(u16x4*)(o + row * 1024 + tid * 4) = ov;
}

// ---- plain LN (fallback path)
__global__ __launch_bounds__(256)
void ln_k(const u16* __restrict__ x, const u16* __restrict__ g,
          const u16* __restrict__ b, u16* __restrict__ o)
{
    long row = blockIdx.x;
    int tid = threadIdx.x;
    const u16x4 u = *(const u16x4*)(x + row * 1024 + tid * 4);
    float v0 = b2f(u[0]), v1 = b2f(u[1]), v2 = b2f(u[2]), v3 = b2f(u[3]);
    float s  = v0 + v1 + v2 + v3;
    float sq = v0*v0 + v1*v1 + v2*v2 + v3*v3;
    #pragma unroll
    for (int off = 32; off; off >>= 1) { s += __shfl_xor(s, off); sq += __shfl_xor(sq, off); }
    __shared__ float sm[8];
    int wid = tid >> 6, lane = tid & 63;
    if (lane == 0) { sm[wid] = s; sm[wid + 4] = sq; }
    __syncthreads();
    s  = sm[0] + sm[1] + sm[2] + sm[3];
    sq = sm[4] + sm[5] + sm[6] + sm[7];
    float mean = s * (1.0f / 1024.0f);
    float var  = sq * (1.0f / 1024.0f) - mean * mean;
    float rs   = rsqrtf(var + 1e-5f);
    u16x4 gg = *(const u16x4*)(g + tid * 4);
    u16x4 bb = *(const u16x4*)(b + tid * 4);
    u16x4 ov;
    ov[0] = f2b((v0 - mean) * rs * b2f(gg[0]) + b2f(bb[0]));
    ov[1] = f2b((v1 - mean) * rs * b2f(gg[1]) + b2f(bb[1]));
    ov[2] = f2b((v2 - mean) * rs * b2f(gg[2]) + b2f(bb[2]));
    ov[3] = f2b((v3 - mean) * rs * b2f(gg[3]) + b2f(bb[3]));
    *(u16x4*)(o + row * 1024 + tid * 4) = ov;
}

// ---- fused split-K(2) reduce + LN2
__global__ __launch_bounds__(256)
void redln_k(const float* __restrict__ P, long slice,
             const u16* __restrict__ bias, u16* __restrict__ res,
             const u16* __restrict__ g, const u16* __restrict__ b,
             u16* __restrict__ o)
{
    long row = blockIdx.x;
    int tid = threadIdx.x;
    long i = row * 1024 + tid * 4;
    float4 v  = *(const float4*)(P + i);
    float4 p1 = *(const float4*)(P + slice + i);
    u16x4 bb = *(const u16x4*)(bias + tid * 4);
    u16x4 rr = *(const u16x4*)(res + i);
    float v0 = b2f(f2b(v.x + p1.x + b2f(bb[0]) + b2f(rr[0])));
    float v1 = b2f(f2b(v.y + p1.y + b2f(bb[1]) + b2f(rr[1])));
    float v2 = b2f(f2b(v.z + p1.z + b2f(bb[2]) + b2f(rr[2])));
    float v3 = b2f(f2b(v.w + p1.w + b2f(bb[3]) + b2f(rr[3])));
    u16x4 xv; xv[0] = f2b(v0); xv[1] = f2b(v1); xv[2] = f2b(v2); xv[3] = f2b(v3);
    *(u16x4*)(res + i) = xv;
    float s  = v0 + v1 + v2 + v3;
    float sq = v0*v0 + v1*v1 + v2*v2 + v3*v3;
    #pragma unroll
    for (int off = 32; off; off >>= 1) { s += __shfl_xor(s, off); sq += __shfl_xor(sq, off); }
    __shared__ float sm[8];
    int wid = tid >> 6, lane = tid & 63;
    if (lane == 0) { sm[wid] = s; sm[wid + 4] = sq; }
    __syncthreads();
    s  = sm[0] + sm[1] + sm[2] + sm[3];
    sq = sm[4] + sm[5] + sm[6] + sm[7];
    float mean = s * (1.0f / 1024.0f);
    float var  = sq * (1.0f / 1024.0f) - mean * mean;
    float rs   = rsqrtf(var + 1e-5f);
    u16x4 gg = *(const u16x4*)(g + tid * 4);
    u16x4 b2 = *(const u16x4*)(b + tid * 4);
    u16x4 ov;
    ov[0] = f2b((v0 - mean) * rs * b2f(gg[0]) + b2f(b2[0]));
    ov[1] = f2b((v1 - mean) * rs * b2f(gg[1]) + b2f(b2[1]));
    ov[2] = f2b((v2 - mean) * rs * b2f(gg[2]) + b2f(b2[2]));
    ov[3] = f2b((v3 - mean) * rs * b2f(gg[3]) + b2f(b2[3]));
    *(u16x4*)(o + row * 1024 + tid * 4) = ov;
}

// -------- Fused softmax (causal, in-place) + mean-over-heads ----------
__global__ __launch_bounds__(1024)
void smmean_k(u16* __restrict__ probs, void* __restrict__ ow, long ofs,
              const int* __restrict__ flag)
{
    const long MEG = 1L << 20;
    __shared__ float red[16 * 1024];
    int bl = blockIdx.x >> 10;           // batch within chunk
    int q  = blockIdx.x & 1023;
    int w = threadIdx.x >> 6, lane = threadIdx.x & 63;
    int tile_end = ((q >> 7) + 1) << 7;
    u16* row = probs + (((long)(bl * 16 + w)) << 20) + (long)q * 1024;
    float v[16];
    float m = -3.0e38f;
    #pragma unroll
    for (int c = 0; c < 2; c++) {
        int kb = (c * 64 + lane) * 8;
        if (kb <= q) {
            u16x8 u = *(const u16x8*)(row + kb);
            #pragma unroll
            for (int e = 0; e < 8; e++) {
                if (kb + e <= q) {
                    float f = b2f(u[e]);
                    v[c * 8 + e] = f;
                    m = fmaxf(m, f);
                } else v[c * 8 + e] = -3.0e38f;
            }
        } else {
            #pragma unroll
            for (int e = 0; e < 8; e++) v[c * 8 + e] = -3.0e38f;
        }
    }
    #pragma unroll
    for (int off = 32; off; off >>= 1) m = fmaxf(m, __shfl_xor(m, off));
    float s = 0.0f;
    #pragma unroll
    for (int t = 0; t < 16; t++) {
        float e = (v[t] > -1.0e38f) ? __expf(v[t] - m) : 0.0f;
        v[t] = e; s += e;
    }
    #pragma unroll
    for (int off = 32; off; off >>= 1) s += __shfl_xor(s, off);
    float inv = 1.0f / s;
    #pragma unroll
    for (int c = 0; c < 2; c++) {
        int kb = (c * 64 + lane) * 8;
        float p[8];
        #pragma unroll
        for (int e = 0; e < 8; e++) p[e] = v[c * 8 + e] * inv;
        #pragma unroll
        for (int e = 0; e < 8; e++) red[w * 1024 + kb + e] = p[e];
        if (kb < tile_end) {
            u16x8 o;
            #pragma unroll
            for (int e = 0; e < 8; e++) o[e] = f2b(p[e]);
            *(u16x8*)(row + kb) = o;
        }
    }
    __syncthreads();
    int t = threadIdx.x;
    float acc = 0.0f;
    #pragma unroll
    for (int h = 0; h < 16; h++) acc += red[h * 1024 + t];
    acc *= 0.0625f;
    long idx = ofs + (long)bl * MEG + (long)q * 1024 + t;
    if (*flag) ((float*)ow)[idx] = acc;
    else       ((u16*)ow)[idx]   = f2b(acc);
}

// -------- split-K(4) reduce for final output --------
__global__ __launch_bounds__(256)
void reduce_out_k(const float* __restrict__ P, long slice,
                  const u16* __restrict__ bias, const u16* __restrict__ res,
                  void* __restrict__ out, const int* __restrict__ flag)
{
    long i = ((long)blockIdx.x * 256 + threadIdx.x) * 4;
    int gn = (int)(i & 1023);
    float4 v = *(const float4*)(P + i);
    #pragma unroll
    for (int s = 1; s < 4; s++) {
        const float4 p = *(const float4*)(P + (long)s * slice + i);
        v.x += p.x; v.y += p.y; v.z += p.z; v.w += p.w;
    }
    u16x4 bb = *(const u16x4*)(bias + gn);
    u16x4 rr = *(const u16x4*)(res + i);
    v.x += b2f(bb[0]) + b2f(rr[0]);
    v.y += b2f(bb[1]) + b2f(rr[1]);
    v.z += b2f(bb[2]) + b2f(rr[2]);
    v.w += b2f(bb[3]) + b2f(rr[3]);
    if (*flag) {
        *(float4*)((float*)out + i) = v;
    } else {
        u16x4 o;
        o[0] = f2b(v.x); o[1] = f2b(v.y); o[2] = f2b(v.z); o[3] = f2b(v.w);
        *(u16x4*)((u16*)out + i) = o;
    }
}

// ======== g8: 256x256x(BK=64) 8-phase deep-pipelined GEMM =============
// C[m,n] = sum_k A[m,k] * Bt[n,k]  (+ epilogue).  EPI: 3 gelu(+bias)->bf16,
// 7 split-K fp32 partial.  Requires NT = K/64 even and >= 2.
// Even K-tiles -> buf0, odd -> buf1; 4 (Ahalf,Bhalf) phases per K-tile.
// Main loop runs it < NT-2 so EVERY stage call is in range and the FIFO
// vmcnt math is exact (R4 bug: skipped tail stages weakened the counted
// waits -> stale LDS reads of the last K-tile). Steady-state staging:
//   P1:(t+1).A1  P2:(t+1).B1  P3:(t+2).A0  P4:(t+2).B0
//   P5:(t+2).A1  P6:(t+2).B1  P7:(t+3).A0  P8:(t+3).B0
// with waits 6@P1, 8@P4, 6@P5, 8@P8 (>=3 half-tiles always in flight).
// The last pair (NT-2, NT-1) is peeled: stages only (NT-1).A1/B1, waits
// 6@Pe1 then a single vmcnt(0)@Pe4.
// In-row XOR swizzle slot^=(row&7) applied on the global source (keeps
// 128B/8-lane coalescing) and on the ds_read chunk index -> conflict-free
// ds_read_b128 at BK=64.
template<int EPI>
__global__ __launch_bounds__(512, 2)
void g8(const u16* __restrict__ A, const u16* __restrict__ Bt,
        u16* __restrict__ C, const u16* __restrict__ bias,
        float* __restrict__ Cf,
        int K, int lda, int ldb, int ldc,
        long sA, long sB, long sC)
{
    __shared__ alignas(16) u16 shA[2 * 16384];   // 64 KB
    __shared__ alignas(16) u16 shB[2 * 16384];   // 64 KB

    const int tid = threadIdx.x;
    int tn = blockIdx.x, tm = blockIdx.y;
    const int bz = blockIdx.z;
    {   // XCD-aware swizzle; requires gridDim.y % 8 == 0
        int L = blockIdx.y * gridDim.x + blockIdx.x;
        int xcd = L & 7, idx = L >> 3;
        tn = idx % gridDim.x;
        tm = (idx / gridDim.x) * 8 + xcd;
    }
    const u16* Ab = A + (long)bz * sA;
    const u16* Bb = Bt + (long)bz * sB;
    const int m0 = tm * 256, n0 = tn * 256;
    const int NT = K >> 6;

    const int w = tid >> 6, lane = tid & 63;
    const int lr = lane & 15, quad = lane >> 4, sw = lane & 7;
    const int wm16 = (w >> 2) * 16, wn16 = (w & 3) * 16;

    auto stageH = [&](int tile, int isB, int half) {
        const u16* src = isB ? Bb : Ab;
        const int ld = isB ? ldb : lda;
        const int r0 = (isB ? n0 : m0) + half * 128;
        u16* dbase = (isB ? shB : shA) + (tile & 1) * 16384 + half * 8192;
        const long kk = (long)tile << 6;
        #pragma unroll
        for (int L2 = 0; L2 < 2; L2++) {
            int c = L2 * 512 + tid;
            int rl = c >> 3, sl = c & 7;
            int kc = sl ^ (rl & 7);
            async16(src + (long)(r0 + rl) * ld + kk + kc * 8, dbase + c * 8);
        }
    };

    f32x4 acc[2][4][2][2] = {};
    s16x8 aF[4][2], b0F[2][2], b1F[2][2];

    auto rdA = [&](int buf, int ih) {
        #pragma unroll
        for (int q = 0; q < 4; q++)
            #pragma unroll
            for (int ks = 0; ks < 2; ks++)
                aF[q][ks] = *(const s16x8*)&shA[buf * 16384 + ih * 8192
                    + (q * 32 + wm16 + lr) * 64 + ((ks * 4 + quad) ^ sw) * 8];
    };
    auto rdB = [&](s16x8 (&bF)[2][2], int buf, int jh) {
        #pragma unroll
        for (int r = 0; r < 2; r++)
            #pragma unroll
            for (int ks = 0; ks < 2; ks++)
                bF[r][ks] = *(const s16x8*)&shB[buf * 16384 + jh * 8192
                    + (r * 64 + wn16 + lr) * 64 + ((ks * 4 + quad) ^ sw) * 8];
    };

#define MM(IH, JH, BF) do { \
    __builtin_amdgcn_s_setprio(1); \
    _Pragma("unroll") \
    for (int q = 0; q < 4; q++) \
        _Pragma("unroll") \
        for (int r = 0; r < 2; r++) \
            _Pragma("unroll") \
            for (int ks = 0; ks < 2; ks++) \
                acc[IH][q][JH][r] = __builtin_amdgcn_mfma_f32_16x16x32_bf16( \
                    aF[q][ks], BF[r][ks], acc[IH][q][JH][r], 0, 0, 0); \
    __builtin_amdgcn_s_setprio(0); \
} while (0)

    // prologue: stage t0 fully + t1.A0,B0 (FIFO order = steady-state slots)
    stageH(0, 0, 0); stageH(0, 1, 0); stageH(0, 0, 1); stageH(0, 1, 1);
    stageH(1, 0, 0); stageH(1, 1, 0);
    VMC(8); BARR();

    for (int it = 0; it < NT - 2; it += 2) {
        // ---- K-tile it (buf0) ----
        rdA(0, 0); rdB(b0F, 0, 0); stageH(it + 1, 0, 1);      // P1
        BARR(); LGKM0(); MM(0, 0, b0F);
        FEN(); VMC(6); BARR();

        rdB(b1F, 0, 1); stageH(it + 1, 1, 1);                 // P2
        BARR(); LGKM0(); MM(0, 1, b1F);
        BARR();

        rdA(0, 1); stageH(it + 2, 0, 0);                      // P3
        BARR(); LGKM0(); MM(1, 0, b0F);
        BARR();

        stageH(it + 2, 1, 0);                                 // P4
        BARR(); LGKM0(); MM(1, 1, b1F);
        FEN(); VMC(8); BARR();

        // ---- K-tile it+1 (buf1) ----
        rdA(1, 0); rdB(b0F, 1, 0); stageH(it + 2, 0, 1);      // P5
        BARR(); LGKM0(); MM(0, 0, b0F);
        FEN(); VMC(6); BARR();

        rdB(b1F, 1, 1); stageH(it + 2, 1, 1);                 // P6
        BARR(); LGKM0(); MM(0, 1, b1F);
        BARR();

        rdA(1, 1); stageH(it + 3, 0, 0);                      // P7
        BARR(); LGKM0(); MM(1, 0, b0F);
        BARR();

        stageH(it + 3, 1, 0);                                 // P8
        BARR(); LGKM0(); MM(1, 1, b1F);
        FEN(); VMC(8); BARR();
    }

    // ---- peeled last pair: tiles NT-2 (buf0), NT-1 (buf1) ----
    // entry outstanding (FIFO): (NT-2).A1, (NT-2).B1, (NT-1).A0, (NT-1).B0
    rdA(0, 0); rdB(b0F, 0, 0); stageH(NT - 1, 0, 1);          // Pe1
    BARR(); LGKM0(); MM(0, 0, b0F);
    FEN(); VMC(6); BARR();                                    // retires (NT-2).A1,B1

    rdB(b1F, 0, 1); stageH(NT - 1, 1, 1);                     // Pe2
    BARR(); LGKM0(); MM(0, 1, b1F);
    BARR();

    rdA(0, 1);                                                // Pe3
    BARR(); LGKM0(); MM(1, 0, b0F);
    BARR();

    BARR(); LGKM0(); MM(1, 1, b1F);                           // Pe4
    FEN(); VMC(0); BARR();                                    // drain all: (NT-1).A0,B0,A1,B1

    rdA(1, 0); rdB(b0F, 1, 0);                                // Pe5
    BARR(); LGKM0(); MM(0, 0, b0F);
    BARR();

    rdB(b1F, 1, 1);                                           // Pe6
    BARR(); LGKM0(); MM(0, 1, b1F);
    BARR();

    rdA(1, 1);                                                // Pe7
    BARR(); LGKM0(); MM(1, 0, b0F);
    BARR();

    LGKM0(); MM(1, 1, b1F);                                   // Pe8
#undef MM

    // epilogue
    #pragma unroll
    for (int ih = 0; ih < 2; ih++)
        #pragma unroll
        for (int q = 0; q < 4; q++)
            #pragma unroll
            for (int jh = 0; jh < 2; jh++)
                #pragma unroll
                for (int r = 0; r < 2; r++)
                    #pragma unroll
                    for (int rr = 0; rr < 4; rr++) {
                        int gm = m0 + ih * 128 + q * 32 + wm16 + quad * 4 + rr;
                        int gn = n0 + jh * 128 + r * 64 + wn16 + lr;
                        float v = acc[ih][q][jh][r][rr];
                        if (EPI == 3) {
                            C[(long)gm * ldc + gn] = f2b(gelu_f(v + b2f(bias[gn])));
                        } else {
                            Cf[(long)bz * sC + (long)gm * ldc + gn] = v;
                        }
                    }
}

// ---------------- gemm_bt: C[m,n] = sum_k A[m,k]*Bt[n,k] + epilogue ---
// (128x128 2-phase kernel; kept for QKV/scores/PV/w_out/fallback paths)
template<int BN, int EPI>
__global__ __launch_bounds__(256)
void gemm_bt(const u16* __restrict__ A, const u16* __restrict__ Bt,
             u16* __restrict__ C, const u16* __restrict__ bias,
             const u16* __restrict__ res,
             u16* __restrict__ qb, u16* __restrict__ kb, u16* __restrict__ vb,
             int M, int N, int K, int lda, int ldb, int ldc,
             long sA, long sB, long sC,
             const int* __restrict__ oflag, void* __restrict__ oout)
{
    constexpr int BM = 128, BK = 32;
    constexpr int WROWS = (BN == 128) ? 2 : 4;
    constexpr int WCOLS = (BN == 128) ? 2 : 1;
    constexpr int WM = BM / WROWS, WN = BN / WCOLS;
    constexpr int MI = WM / 16, NJ = WN / 16;
    constexpr int BCH = BN * BK / 8 / 256;
    constexpr int SHSZ = 2 * BM * BK + 2 * BN * BK;   // u16 units

    __shared__ alignas(16) u16 shmem[SHSZ];
    u16* AshB = shmem;                 // 2 × BM*BK
    u16* BshB = shmem + 2 * BM * BK;   // 2 × BN*BK
    u16* Csh  = shmem;                 // EPI==1 epilogue reuse (16384 u16)

    const int tid = threadIdx.x;
    int tn = blockIdx.x, tm = blockIdx.y;
    const int bz = blockIdx.z;
    if (EPI == 4 && tn > tm) return;

    // XCD-aware swizzle (A-panel locality); requires gridDim.y % 8 == 0
    if (EPI == 1 || EPI == 2 || EPI == 3 || EPI == 6 || EPI == 7) {
        int L = blockIdx.y * gridDim.x + blockIdx.x;
        int xcd = L & 7, idx = L >> 3;
        tn = idx % gridDim.x;
        tm = (idx / gridDim.x) * 8 + xcd;
    }

    const u16* Ab = A + (long)bz * sA;
    const u16* Bb = Bt + (long)bz * sB;

    const int m0 = tm * BM, n0 = tn * BN;
    const int kEff = (EPI == 5) ? (((tm + 1) * BM < K) ? (tm + 1) * BM : K) : K;

    const int w = tid >> 6, lane = tid & 63;
    const int wrow = w % WROWS, wcol = w / WROWS;
    const int mw = wrow * WM, nw = wcol * WN;
    const int lr = lane & 15, quad = lane >> 4;

    const int ca0 = tid, ca1 = 256 + tid;
    const int cb1 = 256 + tid;

    // staging: chunk c -> row c>>2; global k-chunk = (c&3) ^ ((c>>3)&3)
    const int ar0 = ca0 >> 2, ac0 = (((ca0 & 3) ^ ((ca0 >> 3) & 3))) * 8;
    const int ar1 = ca1 >> 2, ac1 = (((ca1 & 3) ^ ((ca1 >> 3) & 3))) * 8;
    const int br0 = tid >> 2, bc0 = (((tid & 3) ^ ((tid >> 3) & 3))) * 8;
    const int br1 = cb1 >> 2, bc1 = (((cb1 & 3) ^ ((cb1 >> 3) & 3))) * 8;

    auto stage = [&](int buf, int k0) {
        async16(Ab + (long)(m0 + ar0) * lda + k0 + ac0, &AshB[buf * BM * BK + ca0 * 8]);
        async16(Ab + (long)(m0 + ar1) * lda + k0 + ac1, &AshB[buf * BM * BK + ca1 * 8]);
        async16(Bb + (long)(n0 + br0) * ldb + k0 + bc0, &BshB[buf * BN * BK + tid * 8]);
        if (BCH == 2)
            async16(Bb + (long)(n0 + br1) * ldb + k0 + bc1, &BshB[buf * BN * BK + cb1 * 8]);
    };

    f32x4 acc[MI][NJ] = {};

    const int foff = (quad ^ ((lr >> 1) & 3)) * 8;

    stage(0, 0);
    int cur = 0;
    for (int k0 = 0; k0 < kEff; k0 += BK) {
        __syncthreads();
        if (k0 + BK < kEff) stage(cur ^ 1, k0 + BK);

        s16x8 af[MI], bfr[NJ];
        #pragma unroll
        for (int i = 0; i < MI; i++)
            af[i] = *(const s16x8*)&AshB[cur * BM * BK + (mw + i * 16 + lr) * BK + foff];
        #pragma unroll
        for (int j = 0; j < NJ; j++)
            bfr[j] = *(const s16x8*)&BshB[cur * BN * BK + (nw + j * 16 + lr) * BK + foff];
        #pragma unroll
        for (int i = 0; i < MI; i++)
            #pragma unroll
            for (int j = 0; j < NJ; j++)
                acc[i][j] = __builtin_amdgcn_mfma_f32_16x16x32_bf16(af[i], bfr[j], acc[i][j], 0, 0, 0);
        cur ^= 1;
    }

    if (EPI == 1) {
        const int sel = n0 >> 10;      // 0=q 1=k 2=v (tile within one section)
        const int b = m0 >> 10, sbase = m0 & 1023;
        if (sel < 2) {
            u16* dst = (sel == 0) ? qb : kb;
            #pragma unroll
            for (int i = 0; i < MI; i++)
                #pragma unroll
                for (int j = 0; j < NJ; j++)
                    #pragma unroll
                    for (int r = 0; r < 4; r++) {
                        int gm = m0 + mw + i * 16 + quad * 4 + r;
                        int gn = n0 + nw + j * 16 + lr;
                        float v = acc[i][j][r] + b2f(bias[gn]);
                        int s = gm & 1023, nn = gn & 1023, hh = nn >> 6, d = nn & 63;
                        dst[(((long)(b * 16 + hh) * 1024 + s) << 6) + d] = f2b(v);
                    }
        } else {
            // v: transpose via XOR-swizzled LDS, then coalesced d-row stores
            __syncthreads();           // all waves done reading A/B staging
            #pragma unroll
            for (int i = 0; i < MI; i++)
                #pragma unroll
                for (int j = 0; j < NJ; j++)
                    #pragma unroll
                    for (int r = 0; r < 4; r++) {
                        int nl = nw + j * 16 + lr;
                        int ml = mw + i * 16 + quad * 4 + r;
                        float v = acc[i][j][r] + b2f(bias[n0 + nl]);
                        Csh[nl * 128 + (((ml >> 3) ^ (nl & 15)) << 3) + (ml & 7)] = f2b(v);
                    }
            __syncthreads();
            const int nv0 = n0 - 2048;
            #pragma unroll
            for (int rep = 0; rep < 8; rep++) {
                int dd = rep * 16 + (tid >> 4);
                int sl = (tid & 15) * 8;
                int dg = nv0 + dd, hh = dg >> 6, dcol = dg & 63;
                u16x8 val = *(const u16x8*)&Csh[dd * 128 + ((((sl >> 3)) ^ (dd & 15)) << 3)];
                *(u16x8*)&vb[(((long)(b * 16 + hh) * 64 + dcol) << 10) + sbase + sl] = val;
            }
        }
        return;
    }

    u16* Cb;
    if (EPI == 5) Cb = C + (long)(bz >> 4) * (1 << 20) + (bz & 15) * 64;
    else          Cb = C + (long)bz * sC;

    #pragma unroll
    for (int i = 0; i < MI; i++) {
        #pragma unroll
        for (int j = 0; j < NJ; j++) {
            #pragma unroll
            for (int r = 0; r < 4; r++) {
                int gm = m0 + mw + i * 16 + quad * 4 + r;
                int gn = n0 + nw + j * 16 + lr;
                float v = acc[i][j][r];
                if (EPI == 5) {
                    Cb[(long)gm * ldc + gn] = f2b(v);
                } else if (EPI == 2) {
                    v += b2f(bias[gn]) + b2f(res[(long)gm * ldc + gn]);
                    Cb[(long)gm * ldc + gn] = f2b(v);
                } else if (EPI == 3) {
                    Cb[(long)gm * ldc + gn] = f2b(gelu_f(v + b2f(bias[gn])));
                } else if (EPI == 4) {
                    if (gn <= gm) Cb[(long)gm * ldc + gn] = f2b(v * 0.125f);
                } else if (EPI == 6) {
                    v += b2f(bias[gn]) + b2f(res[(long)gm * ldc + gn]);
                    long idx = (long)gm * ldc + gn;
                    if (*oflag) ((float*)oout)[idx] = v;
                    else        ((u16*)oout)[idx]   = f2b(v);
                } else if (EPI == 7) {
                    ((float*)oout)[(long)bz * sC + (long)gm * ldc + gn] = v;
                }
            }
        }
    }
}

extern "C" void kernel_launch(void* const* d_in, const int* in_sizes, int n_in,
                              void* d_out, int out_size, void* d_ws, size_t ws_size,
                              hipStream_t stream)
{
    const long MEG = 1L << 20;
    const long KI  = 1024;

    u16* ws = (u16*)d_ws;
    u16* xc    = ws;                    // 4Mi: bf16 x, becomes x2 in-place
    u16* winC  = ws + 4  * MEG;         // 3Mi
    u16* woutC = ws + 7  * MEG;         // 1Mi
    u16* wfcC  = ws + 8  * MEG;         // 4Mi
    u16* wprjC = ws + 12 * MEG;         // 4Mi
    u16* sm    = ws + 16 * MEG;
    u16* ln1g = sm + 0*4*KI, *ln1b = sm + 1*4*KI;
    u16* ln2g = sm + 2*4*KI, *ln2b = sm + 3*4*KI;
    u16* binC = sm + 4*4*KI;
    u16* boutC= sm + 5*4*KI;
    u16* bfcC = sm + 6*4*KI;
    u16* bprjC= sm + 7*4*KI;
    int* flag = (int*)(sm + 8*4*KI);
    u16* slotA = ws + 16 * MEG + 64 * KI;   // 4Mi: h / att / h2
    u16* qB    = slotA + 4  * MEG;
    u16* kB    = slotA + 8  * MEG;
    u16* vT    = slotA + 12 * MEG;
    u16* probs = slotA + 16 * MEG;      // chunk*(H,S,S); [0,16Mi) reused as act
    float* part = (float*)(probs + 16 * MEG);  // split-K partials (chunk=4 only)

    const long fixed_elems = 32 * MEG + 64 * KI;
    const long avail = (long)(ws_size / 2);
    int chunk = 1;
    if      (avail >= fixed_elems + 64 * MEG) chunk = 4;
    else if (avail >= fixed_elems + 32 * MEG) chunk = 2;
    const bool splitk = (chunk == 4);

    hipMemsetAsync((void*)flag, 0, sizeof(int), stream);
    detect_k<<<32, 256, 0, stream>>>((const u16*)d_in[0], flag);
    conv_w_k<<<12288, 256, 0, stream>>>(d_in[6], d_in[8], d_in[10], d_in[12],
                                        winC, flag);
    conv_small_k<<<52, 256, 0, stream>>>(d_in[2], d_in[3], d_in[4], d_in[5],
                                         d_in[7], d_in[9], d_in[11], d_in[13],
                                         sm, flag);

    u16* h   = slotA;
    u16* att = slotA;
    u16* h2  = slotA;
    u16* act = probs;

    // 1. LN1 (+x conversion)
    ln1x_k<<<4096, 256, 0, stream>>>(d_in[0], ln1g, ln1b, xc, h, flag);
    // 2. QKV projection
    gemm_bt<128, 1><<<dim3(24, 32, 1), 256, 0, stream>>>(
        h, winC, nullptr, binC, nullptr, qB, kB, vT,
        4096, 3072, 1024, 1024, 1024, 0, 0, 0, 0, nullptr, nullptr);
    // 3-6. attention
    for (int b0 = 0; b0 < 4; b0 += chunk) {
        gemm_bt<128, 4><<<dim3(8, 8, 16 * chunk), 256, 0, stream>>>(
            qB + b0 * MEG, kB + b0 * MEG, probs, nullptr, nullptr,
            nullptr, nullptr, nullptr,
            1024, 1024, 64, 64, 64, 1024, 65536, 65536, 1048576, nullptr, nullptr);
        smmean_k<<<1024 * chunk, 1024, 0, stream>>>(probs, d_out,
                                                    4 * MEG + b0 * MEG, flag);
        gemm_bt<64, 5><<<dim3(1, 8, 16 * chunk), 256, 0, stream>>>(
            probs, vT + b0 * MEG, att + b0 * MEG, nullptr, nullptr,
            nullptr, nullptr, nullptr,
            1024, 64, 1024, 1024, 1024, 1024, 1048576, 65536, 0, nullptr, nullptr);
    }
    // 7+8. x2 = x + att @ w_out^T + b_out; h2 = LN2(x2)
    if (splitk) {
        gemm_bt<128, 7><<<dim3(8, 32, 2), 256, 0, stream>>>(
            att, woutC, nullptr, nullptr, nullptr, nullptr, nullptr, nullptr,
            4096, 1024, 512, 1024, 1024, 1024, 512, 512, 4 * MEG, nullptr, part);
        redln_k<<<4096, 256, 0, stream>>>(part, 4 * MEG, boutC, xc, ln2g, ln2b, h2);
    } else {
        gemm_bt<128, 2><<<dim3(8, 32, 1), 256, 0, stream>>>(
            att, woutC, xc, boutC, xc, nullptr, nullptr, nullptr,
            4096, 1024, 1024, 1024, 1024, 1024, 0, 0, 0, nullptr, nullptr);
        ln_k<<<4096, 256, 0, stream>>>(xc, ln2g, ln2b, h2);
    }
    // 9. act = gelu(h2 @ w_fc^T + b_fc)   [256^2 8-phase kernel]
    g8<3><<<dim3(16, 16, 1), 512, 0, stream>>>(
        h2, wfcC, act, bfcC, nullptr,
        1024, 1024, 1024, 4096, 0, 0, 0);
    // 10. out = x2 + act @ w_proj^T + b_proj
    if (splitk) {
        g8<7><<<dim3(4, 16, 4), 512, 0, stream>>>(
            act, wprjC, nullptr, nullptr, part,
            1024, 4096, 4096, 1024, 1024, 1024, 4 * MEG);
        reduce_out_k<<<4096, 256, 0, stream>>>(part, 4 * MEG, bprjC, xc, d_out, flag);
    } else {
        gemm_bt<128, 6><<<dim3(8, 32, 1), 256, 0, stream>>>(
            act, wprjC, nullptr, bprjC, xc, nullptr, nullptr, nullptr,
            4096, 1024, 4096, 4096, 4096, 1024, 0, 0, 0, flag, d_out);
    }
}

// Round 6
// 412.487 us; speedup vs baseline: 1.2225x; 1.0100x over previous
//
#include <hip/hip_runtime.h>

typedef unsigned short u16;
typedef u16   u16x4 __attribute__((ext_vector_type(4)));
typedef u16   u16x8 __attribute__((ext_vector_type(8)));
typedef short s16x8 __attribute__((ext_vector_type(8)));
typedef float f32x4 __attribute__((ext_vector_type(4)));

__device__ __forceinline__ float b2f(u16 u) {
    union { unsigned int i; float f; } v; v.i = ((unsigned int)u) << 16; return v.f;
}
__device__ __forceinline__ u16 f2b(float f) {
    union { float f; unsigned int i; } v; v.f = f;
    unsigned int r = v.i + 0x7fffu + ((v.i >> 16) & 1u);
    return (u16)(r >> 16);
}
__device__ __forceinline__ float gelu_f(float x) {
    float z = 0.7978845608028654f * (x + 0.044715f * x * x * x);
    float e = __expf(2.0f * z);
    float t = 1.0f - 2.0f / (e + 1.0f);
    return 0.5f * x * (1.0f + t);
}
__device__ __forceinline__ void async16(const u16* g, u16* l) {
    __builtin_amdgcn_global_load_lds(
        (const __attribute__((address_space(1))) unsigned int*)g,
        (__attribute__((address_space(3))) unsigned int*)l,
        16, 0, 0);
}

#define FEN() asm volatile("" ::: "memory")
#define BARR() { FEN(); __builtin_amdgcn_s_barrier(); FEN(); }
#define LGKM0() { asm volatile("s_waitcnt lgkmcnt(0)" ::: "memory"); __builtin_amdgcn_sched_barrier(0); }
#define VMC(N) asm volatile("s_waitcnt vmcnt(" #N ")" ::: "memory")

// ---- dtype detector: bf16-read exponent >= 2^60 anywhere => fp32 input
__global__ __launch_bounds__(256)
void detect_k(const u16* __restrict__ x, int* __restrict__ flag)
{
    int gid = blockIdx.x * 256 + threadIdx.x;
    const u16x8 u = *(const u16x8*)(x + (long)gid * 8);
    int bad = 0;
    #pragma unroll
    for (int e = 0; e < 8; e++) {
        int ex = (u[e] >> 7) & 0xFF;
        if (ex >= 187) bad = 1;
    }
    unsigned long long m = __ballot(bad != 0);
    if ((threadIdx.x & 63) == 0 && m != 0ull) atomicOr(flag, 1);
}

// ---- weight converter (vec4): w_in|w_out|w_fc|w_proj -> ws[4Mi..16Mi)
__global__ __launch_bounds__(256)
void conv_w_k(const void* __restrict__ s0, const void* __restrict__ s1,
              const void* __restrict__ s2, const void* __restrict__ s3,
              u16* __restrict__ dst, const int* __restrict__ flag)
{
    const long MEG = 1L << 20;
    long gid = ((long)blockIdx.x * 256 + threadIdx.x) * 4;   // < 12Mi
    const void* s; long off;
    if      (gid <  3*MEG) { s = s0; off = gid; }
    else if (gid <  4*MEG) { s = s1; off = gid - 3*MEG; }
    else if (gid <  8*MEG) { s = s2; off = gid - 4*MEG; }
    else                   { s = s3; off = gid - 8*MEG; }
    u16x4 o;
    if (*flag) {
        const float4 f = *(const float4*)((const float*)s + off);
        o[0] = f2b(f.x); o[1] = f2b(f.y); o[2] = f2b(f.z); o[3] = f2b(f.w);
    } else {
        o = *(const u16x4*)((const u16*)s + off);
    }
    *(u16x4*)(dst + gid) = o;
}

// ---- fused small-param converter into 4Ki-slotted region
__global__ __launch_bounds__(256)
void conv_small_k(const void* s0, const void* s1, const void* s2, const void* s3,
                  const void* s4, const void* s5, const void* s6, const void* s7,
                  u16* __restrict__ dst, const int* __restrict__ flag)
{
    int gid = blockIdx.x * 256 + threadIdx.x;          // < 13312
    int seg, off;
    if      (gid <  4096) { seg = gid >> 10;  off = gid & 1023; }
    else if (gid <  7168) { seg = 4; off = gid - 4096; }
    else if (gid <  8192) { seg = 5; off = gid - 7168; }
    else if (gid < 12288) { seg = 6; off = gid - 8192; }
    else                  { seg = 7; off = gid - 12288; }
    const void* srcs[8] = {s0, s1, s2, s3, s4, s5, s6, s7};
    const void* s = srcs[seg];
    dst[seg * 4096 + off] = (*flag) ? f2b(((const float*)s)[off]) : ((const u16*)s)[off];
}

// ---- LN1 fused with x conversion
__global__ __launch_bounds__(256)
void ln1x_k(const void* __restrict__ xraw, const u16* __restrict__ g,
            const u16* __restrict__ b, u16* __restrict__ xc,
            u16* __restrict__ o, const int* __restrict__ flag)
{
    long row = blockIdx.x;
    int tid = threadIdx.x;
    float v0, v1, v2, v3;
    if (*flag) {
        const float4 f = *(const float4*)((const float*)xraw + row * 1024 + tid * 4);
        v0 = b2f(f2b(f.x)); v1 = b2f(f2b(f.y));
        v2 = b2f(f2b(f.z)); v3 = b2f(f2b(f.w));
    } else {
        const u16x4 u = *(const u16x4*)((const u16*)xraw + row * 1024 + tid * 4);
        v0 = b2f(u[0]); v1 = b2f(u[1]); v2 = b2f(u[2]); v3 = b2f(u[3]);
    }
    u16x4 xv; xv[0] = f2b(v0); xv[1] = f2b(v1); xv[2] = f2b(v2); xv[3] = f2b(v3);
    *(u16x4*)(xc + row * 1024 + tid * 4) = xv;
    float s  = v0 + v1 + v2 + v3;
    float sq = v0*v0 + v1*v1 + v2*v2 + v3*v3;
    #pragma unroll
    for (int off = 32; off; off >>= 1) { s += __shfl_xor(s, off); sq += __shfl_xor(sq, off); }
    __shared__ float sm[8];
    int wid = tid >> 6, lane = tid & 63;
    if (lane == 0) { sm[wid] = s; sm[wid + 4] = sq; }
    __syncthreads();
    s  = sm[0] + sm[1] + sm[2] + sm[3];
    sq = sm[4] + sm[5] + sm[6] + sm[7];
    float mean = s * (1.0f / 1024.0f);
    float var  = sq * (1.0f / 1024.0f) - mean * mean;
    float rs   = rsqrtf(var + 1e-5f);
    u16x4 gg = *(const u16x4*)(g + tid * 4);
    u16x4 bb = *(const u16x4*)(b + tid * 4);
    u16x4 ov;
    ov[0] = f2b((v0 - mean) * rs * b2f(gg[0]) + b2f(bb[0]));
    ov[1] = f2b((v1 - mean) * rs * b2f(gg[1]) + b2f(bb[1]));
    ov[2] = f2b((v2 - mean) * rs * b2f(gg[2]) + b2f(bb[2]));
    ov[3] = f2b((v3 - mean) * rs * b2f(gg[3]) + b2f(bb[3]));
    *(u16x4*)(o + row * 1024 + tid * 4) = ov;
}

// ---- plain LN (fallback path)
__global__ __launch_bounds__(256)
void ln_k(const u16* __restrict__ x, const u16* __restrict__ g,
          const u16* __restrict__ b, u16* __restrict__ o)
{
    long row = blockIdx.x;
    int tid = threadIdx.x;
    const u16x4 u = *(const u16x4*)(x + row * 1024 + tid * 4);
    float v0 = b2f(u[0]), v1 = b2f(u[1]), v2 = b2f(u[2]), v3 = b2f(u[3]);
    float s  = v0 + v1 + v2 + v3;
    float sq = v0*v0 + v1*v1 + v2*v2 + v3*v3;
    #pragma unroll
    for (int off = 32; off; off >>= 1) { s += __shfl_xor(s, off); sq += __shfl_xor(sq, off); }
    __shared__ float sm[8];
    int wid = tid >> 6, lane = tid & 63;
    if (lane == 0) { sm[wid] = s; sm[wid + 4] = sq; }
    __syncthreads();
    s  = sm[0] + sm[1] + sm[2] + sm[3];
    sq = sm[4] + sm[5] + sm[6] + sm[7];
    float mean = s * (1.0f / 1024.0f);
    float var  = sq * (1.0f / 1024.0f) - mean * mean;
    float rs   = rsqrtf(var + 1e-5f);
    u16x4 gg = *(const u16x4*)(g + tid * 4);
    u16x4 bb = *(const u16x4*)(b + tid * 4);
    u16x4 ov;
    ov[0] = f2b((v0 - mean) * rs * b2f(gg[0]) + b2f(bb[0]));
    ov[1] = f2b((v1 - mean) * rs * b2f(gg[1]) + b2f(bb[1]));
    ov[2] = f2b((v2 - mean) * rs * b2f(gg[2]) + b2f(bb[2]));
    ov[3] = f2b((v3 - mean) * rs * b2f(gg[3]) + b2f(bb[3]));
    *(u16x4*)(o + row * 1024 + tid * 4) = ov;
}

// ---- fused split-K(2) reduce + LN2
__global__ __launch_bounds__(256)
void redln_k(const float* __restrict__ P, long slice,
             const u16* __restrict__ bias, u16* __restrict__ res,
             const u16* __restrict__ g, const u16* __restrict__ b,
             u16* __restrict__ o)
{
    long row = blockIdx.x;
    int tid = threadIdx.x;
    long i = row * 1024 + tid * 4;
    float4 v  = *(const float4*)(P + i);
    float4 p1 = *(const float4*)(P + slice + i);
    u16x4 bb = *(const u16x4*)(bias + tid * 4);
    u16x4 rr = *(const u16x4*)(res + i);
    float v0 = b2f(f2b(v.x + p1.x + b2f(bb[0]) + b2f(rr[0])));
    float v1 = b2f(f2b(v.y + p1.y + b2f(bb[1]) + b2f(rr[1])));
    float v2 = b2f(f2b(v.z + p1.z + b2f(bb[2]) + b2f(rr[2])));
    float v3 = b2f(f2b(v.w + p1.w + b2f(bb[3]) + b2f(rr[3])));
    u16x4 xv; xv[0] = f2b(v0); xv[1] = f2b(v1); xv[2] = f2b(v2); xv[3] = f2b(v3);
    *(u16x4*)(res + i) = xv;
    float s  = v0 + v1 + v2 + v3;
    float sq = v0*v0 + v1*v1 + v2*v2 + v3*v3;
    #pragma unroll
    for (int off = 32; off; off >>= 1) { s += __shfl_xor(s, off); sq += __shfl_xor(sq, off); }
    __shared__ float sm[8];
    int wid = tid >> 6, lane = tid & 63;
    if (lane == 0) { sm[wid] = s; sm[wid + 4] = sq; }
    __syncthreads();
    s  = sm[0] + sm[1] + sm[2] + sm[3];
    sq = sm[4] + sm[5] + sm[6] + sm[7];
    float mean = s * (1.0f / 1024.0f);
    float var  = sq * (1.0f / 1024.0f) - mean * mean;
    float rs   = rsqrtf(var + 1e-5f);
    u16x4 gg = *(const u16x4*)(g + tid * 4);
    u16x4 b2 = *(const u16x4*)(b + tid * 4);
    u16x4 ov;
    ov[0] = f2b((v0 - mean) * rs * b2f(gg[0]) + b2f(b2[0]));
    ov[1] = f2b((v1 - mean) * rs * b2f(gg[1]) + b2f(b2[1]));
    ov[2] = f2b((v2 - mean) * rs * b2f(gg[2]) + b2f(b2[2]));
    ov[3] = f2b((v3 - mean) * rs * b2f(gg[3]) + b2f(b2[3]));
    *(u16x4*)(o + row * 1024 + tid * 4) = ov;
}

// -------- Fused softmax (causal, in-place) + mean-over-heads ----------
__global__ __launch_bounds__(1024)
void smmean_k(u16* __restrict__ probs, void* __restrict__ ow, long ofs,
              const int* __restrict__ flag)
{
    const long MEG = 1L << 20;
    __shared__ float red[16 * 1024];
    int bl = blockIdx.x >> 10;           // batch within chunk
    int q  = blockIdx.x & 1023;
    int w = threadIdx.x >> 6, lane = threadIdx.x & 63;
    int tile_end = ((q >> 7) + 1) << 7;
    u16* row = probs + (((long)(bl * 16 + w)) << 20) + (long)q * 1024;
    float v[16];
    float m = -3.0e38f;
    #pragma unroll
    for (int c = 0; c < 2; c++) {
        int kb = (c * 64 + lane) * 8;
        if (kb <= q) {
            u16x8 u = *(const u16x8*)(row + kb);
            #pragma unroll
            for (int e = 0; e < 8; e++) {
                if (kb + e <= q) {
                    float f = b2f(u[e]);
                    v[c * 8 + e] = f;
                    m = fmaxf(m, f);
                } else v[c * 8 + e] = -3.0e38f;
            }
        } else {
            #pragma unroll
            for (int e = 0; e < 8; e++) v[c * 8 + e] = -3.0e38f;
        }
    }
    #pragma unroll
    for (int off = 32; off; off >>= 1) m = fmaxf(m, __shfl_xor(m, off));
    float s = 0.0f;
    #pragma unroll
    for (int t = 0; t < 16; t++) {
        float e = (v[t] > -1.0e38f) ? __expf(v[t] - m) : 0.0f;
        v[t] = e; s += e;
    }
    #pragma unroll
    for (int off = 32; off; off >>= 1) s += __shfl_xor(s, off);
    float inv = 1.0f / s;
    #pragma unroll
    for (int c = 0; c < 2; c++) {
        int kb = (c * 64 + lane) * 8;
        float p[8];
        #pragma unroll
        for (int e = 0; e < 8; e++) p[e] = v[c * 8 + e] * inv;
        #pragma unroll
        for (int e = 0; e < 8; e++) red[w * 1024 + kb + e] = p[e];
        if (kb < tile_end) {
            u16x8 o;
            #pragma unroll
            for (int e = 0; e < 8; e++) o[e] = f2b(p[e]);
            *(u16x8*)(row + kb) = o;
        }
    }
    __syncthreads();
    int t = threadIdx.x;
    float acc = 0.0f;
    #pragma unroll
    for (int h = 0; h < 16; h++) acc += red[h * 1024 + t];
    acc *= 0.0625f;
    long idx = ofs + (long)bl * MEG + (long)q * 1024 + t;
    if (*flag) ((float*)ow)[idx] = acc;
    else       ((u16*)ow)[idx]   = f2b(acc);
}

// -------- split-K(4) reduce for final output --------
__global__ __launch_bounds__(256)
void reduce_out_k(const float* __restrict__ P, long slice,
                  const u16* __restrict__ bias, const u16* __restrict__ res,
                  void* __restrict__ out, const int* __restrict__ flag)
{
    long i = ((long)blockIdx.x * 256 + threadIdx.x) * 4;
    int gn = (int)(i & 1023);
    float4 v = *(const float4*)(P + i);
    #pragma unroll
    for (int s = 1; s < 4; s++) {
        const float4 p = *(const float4*)(P + (long)s * slice + i);
        v.x += p.x; v.y += p.y; v.z += p.z; v.w += p.w;
    }
    u16x4 bb = *(const u16x4*)(bias + gn);
    u16x4 rr = *(const u16x4*)(res + i);
    v.x += b2f(bb[0]) + b2f(rr[0]);
    v.y += b2f(bb[1]) + b2f(rr[1]);
    v.z += b2f(bb[2]) + b2f(rr[2]);
    v.w += b2f(bb[3]) + b2f(rr[3]);
    if (*flag) {
        *(float4*)((float*)out + i) = v;
    } else {
        u16x4 o;
        o[0] = f2b(v.x); o[1] = f2b(v.y); o[2] = f2b(v.z); o[3] = f2b(v.w);
        *(u16x4*)((u16*)out + i) = o;
    }
}

// ======== g8: 256x256x(BK=64) 8-phase deep-pipelined GEMM =============
// C[m,n] = sum_k A[m,k] * Bt[n,k]  (+ epilogue).  EPI: 3 gelu(+bias)->bf16,
// 7 split-K fp32 partial.  Requires NT = K/64 even and >= 2.
// Even K-tiles -> buf0, odd -> buf1; 4 (Ahalf,Bhalf) phases per K-tile:
//   P1 reads A0,B0; P2 reads B1; P3 reads A1; P4 register-only.
// Staging slots (R6 fix — no wait may target a same/adjacent-phase load):
//   P1(t): (t+1).B1   [WAR: (t-1).B1 last read P2(t-1); RAW: read P2(t+1), 5 ph]
//   P2(t): (t+2).A0   [WAR: (t).A0 last read P1(t);    RAW: read P1(t+2), 7 ph]
//   P3(t): (t+2).B0   [WAR: (t).B0 last read P1(t);    RAW: read P1(t+2), 6 ph]
//   P4(t): (t+1).A1   [WAR: (t-1).A1 last read P3(t-1);RAW: read P3(t+1), 3 ph]
// Waits (FIFO-counted, targets >= 2 phases old):
//   VMC(8) @end-P1: retires (t).B1   (issued P1(t-1), 4 phases earlier)
//   VMC(4) @end-P2: retires (t).A1   (issued P4(t-1), 2 phases earlier)
//                   + implicitly (t+1).A0/B0 -> covers next P1, no P4 wait.
// Ledger (loads): enter P1 @8 -> 10 -> W 8 -> 10 -> W 4 -> 6 -> 8. Never
// drained in the main loop. Last two tiles peeled with VMC(8)/(2), (2)/(0).
// In-row XOR swizzle slot^=(row&7) on the global source (keeps 128B/8-lane
// coalescing) and on the ds_read chunk index -> conflict-free ds_read_b128.
template<int EPI>
__global__ __launch_bounds__(512, 2)
void g8(const u16* __restrict__ A, const u16* __restrict__ Bt,
        u16* __restrict__ C, const u16* __restrict__ bias,
        float* __restrict__ Cf,
        int K, int lda, int ldb, int ldc,
        long sA, long sB, long sC)
{
    __shared__ alignas(16) u16 shA[2 * 16384];   // 64 KB
    __shared__ alignas(16) u16 shB[2 * 16384];   // 64 KB

    const int tid = threadIdx.x;
    int tn = blockIdx.x, tm = blockIdx.y;
    const int bz = blockIdx.z;
    {   // XCD-aware swizzle; requires gridDim.y % 8 == 0
        int L = blockIdx.y * gridDim.x + blockIdx.x;
        int xcd = L & 7, idx = L >> 3;
        tn = idx % gridDim.x;
        tm = (idx / gridDim.x) * 8 + xcd;
    }
    const u16* Ab = A + (long)bz * sA;
    const u16* Bb = Bt + (long)bz * sB;
    const int m0 = tm * 256, n0 = tn * 256;
    const int NT = K >> 6;

    const int w = tid >> 6, lane = tid & 63;
    const int lr = lane & 15, quad = lane >> 4, sw = lane & 7;
    const int wm16 = (w >> 2) * 16, wn16 = (w & 3) * 16;

    auto stageH = [&](int tile, int isB, int half) {
        const u16* src = isB ? Bb : Ab;
        const int ld = isB ? ldb : lda;
        const int r0 = (isB ? n0 : m0) + half * 128;
        u16* dbase = (isB ? shB : shA) + (tile & 1) * 16384 + half * 8192;
        const long kk = (long)tile << 6;
        #pragma unroll
        for (int L2 = 0; L2 < 2; L2++) {
            int c = L2 * 512 + tid;
            int rl = c >> 3, sl = c & 7;
            int kc = sl ^ (rl & 7);
            async16(src + (long)(r0 + rl) * ld + kk + kc * 8, dbase + c * 8);
        }
    };

    f32x4 acc[2][4][2][2] = {};
    s16x8 aF[4][2], b0F[2][2], b1F[2][2];

    auto rdA = [&](int buf, int ih) {
        #pragma unroll
        for (int q = 0; q < 4; q++)
            #pragma unroll
            for (int ks = 0; ks < 2; ks++)
                aF[q][ks] = *(const s16x8*)&shA[buf * 16384 + ih * 8192
                    + (q * 32 + wm16 + lr) * 64 + ((ks * 4 + quad) ^ sw) * 8];
    };
    auto rdB = [&](s16x8 (&bF)[2][2], int buf, int jh) {
        #pragma unroll
        for (int r = 0; r < 2; r++)
            #pragma unroll
            for (int ks = 0; ks < 2; ks++)
                bF[r][ks] = *(const s16x8*)&shB[buf * 16384 + jh * 8192
                    + (r * 64 + wn16 + lr) * 64 + ((ks * 4 + quad) ^ sw) * 8];
    };

#define MM(IH, JH, BF) do { \
    __builtin_amdgcn_s_setprio(1); \
    _Pragma("unroll") \
    for (int q = 0; q < 4; q++) \
        _Pragma("unroll") \
        for (int r = 0; r < 2; r++) \
            _Pragma("unroll") \
            for (int ks = 0; ks < 2; ks++) \
                acc[IH][q][JH][r] = __builtin_amdgcn_mfma_f32_16x16x32_bf16( \
                    aF[q][ks], BF[r][ks], acc[IH][q][JH][r], 0, 0, 0); \
    __builtin_amdgcn_s_setprio(0); \
} while (0)

    // prologue — issue order mirrors steady-state FIFO slots:
    // t0.A0, t0.B0, t0.B1, t1.A0, t1.B0, t0.A1 ; VMC(8) retires t0.A0,B0
    stageH(0, 0, 0); stageH(0, 1, 0); stageH(0, 1, 1);
    stageH(1, 0, 0); stageH(1, 1, 0); stageH(0, 0, 1);
    VMC(8); BARR();

    for (int t = 0; t < NT - 2; ++t) {
        const int buf = t & 1;
        // P1: read A0,B0; stage (t+1).B1
        rdA(buf, 0); rdB(b0F, buf, 0); stageH(t + 1, 1, 1);
        BARR(); LGKM0(); MM(0, 0, b0F);
        FEN(); VMC(8); BARR();
        // P2: read B1; stage (t+2).A0
        rdB(b1F, buf, 1); stageH(t + 2, 0, 0);
        BARR(); LGKM0(); MM(0, 1, b1F);
        FEN(); VMC(4); BARR();
        // P3: read A1; stage (t+2).B0
        rdA(buf, 1); stageH(t + 2, 1, 0);
        BARR(); LGKM0(); MM(1, 0, b0F);
        BARR();
        // P4: stage (t+1).A1
        stageH(t + 1, 0, 1);
        BARR(); LGKM0(); MM(1, 1, b1F);
        BARR();
    }

    // ---- peeled tile NT-2 ----
    {
        const int buf = (NT - 2) & 1;
        rdA(buf, 0); rdB(b0F, buf, 0); stageH(NT - 1, 1, 1);   // P1
        BARR(); LGKM0(); MM(0, 0, b0F);
        FEN(); VMC(8); BARR();                                 // retires (NT-2).B1
        rdB(b1F, buf, 1);                                      // P2 (no stage)
        BARR(); LGKM0(); MM(0, 1, b1F);
        FEN(); VMC(2); BARR();                                 // retires (NT-2).A1 (+older)
        rdA(buf, 1);                                           // P3 (no stage)
        BARR(); LGKM0(); MM(1, 0, b0F);
        BARR();
        stageH(NT - 1, 0, 1);                                  // P4
        BARR(); LGKM0(); MM(1, 1, b1F);
        BARR();
    }
    // ---- peeled tile NT-1 ----
    {
        const int buf = (NT - 1) & 1;
        rdA(buf, 0); rdB(b0F, buf, 0);                         // P1
        BARR(); LGKM0(); MM(0, 0, b0F);
        FEN(); VMC(2); BARR();                                 // retires (NT-1).B1
        rdB(b1F, buf, 1);                                      // P2
        BARR(); LGKM0(); MM(0, 1, b1F);
        FEN(); VMC(0); BARR();                                 // retires (NT-1).A1
        rdA(buf, 1);                                           // P3
        BARR(); LGKM0(); MM(1, 0, b0F);
        BARR();
        LGKM0(); MM(1, 1, b1F);                                // P4
    }
#undef MM

    // epilogue
    #pragma unroll
    for (int ih = 0; ih < 2; ih++)
        #pragma unroll
        for (int q = 0; q < 4; q++)
            #pragma unroll
            for (int jh = 0; jh < 2; jh++)
                #pragma unroll
                for (int r = 0; r < 2; r++)
                    #pragma unroll
                    for (int rr = 0; rr < 4; rr++) {
                        int gm = m0 + ih * 128 + q * 32 + wm16 + quad * 4 + rr;
                        int gn = n0 + jh * 128 + r * 64 + wn16 + lr;
                        float v = acc[ih][q][jh][r][rr];
                        if (EPI == 3) {
                            C[(long)gm * ldc + gn] = f2b(gelu_f(v + b2f(bias[gn])));
                        } else {
                            Cf[(long)bz * sC + (long)gm * ldc + gn] = v;
                        }
                    }
}

// ---------------- gemm_bt: C[m,n] = sum_k A[m,k]*Bt[n,k] + epilogue ---
// (128x128 2-phase kernel; kept for QKV/scores/PV/fallback paths)
template<int BN, int EPI>
__global__ __launch_bounds__(256)
void gemm_bt(const u16* __restrict__ A, const u16* __restrict__ Bt,
             u16* __restrict__ C, const u16* __restrict__ bias,
             const u16* __restrict__ res,
             u16* __restrict__ qb, u16* __restrict__ kb, u16* __restrict__ vb,
             int M, int N, int K, int lda, int ldb, int ldc,
             long sA, long sB, long sC,
             const int* __restrict__ oflag, void* __restrict__ oout)
{
    constexpr int BM = 128, BK = 32;
    constexpr int WROWS = (BN == 128) ? 2 : 4;
    constexpr int WCOLS = (BN == 128) ? 2 : 1;
    constexpr int WM = BM / WROWS, WN = BN / WCOLS;
    constexpr int MI = WM / 16, NJ = WN / 16;
    constexpr int BCH = BN * BK / 8 / 256;
    constexpr int SHSZ = 2 * BM * BK + 2 * BN * BK;   // u16 units

    __shared__ alignas(16) u16 shmem[SHSZ];
    u16* AshB = shmem;                 // 2 × BM*BK
    u16* BshB = shmem + 2 * BM * BK;   // 2 × BN*BK
    u16* Csh  = shmem;                 // EPI==1 epilogue reuse (16384 u16)

    const int tid = threadIdx.x;
    int tn = blockIdx.x, tm = blockIdx.y;
    const int bz = blockIdx.z;
    if (EPI == 4 && tn > tm) return;

    // XCD-aware swizzle (A-panel locality); requires gridDim.y % 8 == 0
    if (EPI == 1 || EPI == 2 || EPI == 3 || EPI == 6 || EPI == 7) {
        int L = blockIdx.y * gridDim.x + blockIdx.x;
        int xcd = L & 7, idx = L >> 3;
        tn = idx % gridDim.x;
        tm = (idx / gridDim.x) * 8 + xcd;
    }

    const u16* Ab = A + (long)bz * sA;
    const u16* Bb = Bt + (long)bz * sB;

    const int m0 = tm * BM, n0 = tn * BN;
    const int kEff = (EPI == 5) ? (((tm + 1) * BM < K) ? (tm + 1) * BM : K) : K;

    const int w = tid >> 6, lane = tid & 63;
    const int wrow = w % WROWS, wcol = w / WROWS;
    const int mw = wrow * WM, nw = wcol * WN;
    const int lr = lane & 15, quad = lane >> 4;

    const int ca0 = tid, ca1 = 256 + tid;
    const int cb1 = 256 + tid;

    // staging: chunk c -> row c>>2; global k-chunk = (c&3) ^ ((c>>3)&3)
    const int ar0 = ca0 >> 2, ac0 = (((ca0 & 3) ^ ((ca0 >> 3) & 3))) * 8;
    const int ar1 = ca1 >> 2, ac1 = (((ca1 & 3) ^ ((ca1 >> 3) & 3))) * 8;
    const int br0 = tid >> 2, bc0 = (((tid & 3) ^ ((tid >> 3) & 3))) * 8;
    const int br1 = cb1 >> 2, bc1 = (((cb1 & 3) ^ ((cb1 >> 3) & 3))) * 8;

    auto stage = [&](int buf, int k0) {
        async16(Ab + (long)(m0 + ar0) * lda + k0 + ac0, &AshB[buf * BM * BK + ca0 * 8]);
        async16(Ab + (long)(m0 + ar1) * lda + k0 + ac1, &AshB[buf * BM * BK + ca1 * 8]);
        async16(Bb + (long)(n0 + br0) * ldb + k0 + bc0, &BshB[buf * BN * BK + tid * 8]);
        if (BCH == 2)
            async16(Bb + (long)(n0 + br1) * ldb + k0 + bc1, &BshB[buf * BN * BK + cb1 * 8]);
    };

    f32x4 acc[MI][NJ] = {};

    const int foff = (quad ^ ((lr >> 1) & 3)) * 8;

    stage(0, 0);
    int cur = 0;
    for (int k0 = 0; k0 < kEff; k0 += BK) {
        __syncthreads();
        if (k0 + BK < kEff) stage(cur ^ 1, k0 + BK);

        s16x8 af[MI], bfr[NJ];
        #pragma unroll
        for (int i = 0; i < MI; i++)
            af[i] = *(const s16x8*)&AshB[cur * BM * BK + (mw + i * 16 + lr) * BK + foff];
        #pragma unroll
        for (int j = 0; j < NJ; j++)
            bfr[j] = *(const s16x8*)&BshB[cur * BN * BK + (nw + j * 16 + lr) * BK + foff];
        #pragma unroll
        for (int i = 0; i < MI; i++)
            #pragma unroll
            for (int j = 0; j < NJ; j++)
                acc[i][j] = __builtin_amdgcn_mfma_f32_16x16x32_bf16(af[i], bfr[j], acc[i][j], 0, 0, 0);
        cur ^= 1;
    }

    if (EPI == 1) {
        const int sel = n0 >> 10;      // 0=q 1=k 2=v (tile within one section)
        const int b = m0 >> 10, sbase = m0 & 1023;
        if (sel < 2) {
            u16* dst = (sel == 0) ? qb : kb;
            #pragma unroll
            for (int i = 0; i < MI; i++)
                #pragma unroll
                for (int j = 0; j < NJ; j++)
                    #pragma unroll
                    for (int r = 0; r < 4; r++) {
                        int gm = m0 + mw + i * 16 + quad * 4 + r;
                        int gn = n0 + nw + j * 16 + lr;
                        float v = acc[i][j][r] + b2f(bias[gn]);
                        int s = gm & 1023, nn = gn & 1023, hh = nn >> 6, d = nn & 63;
                        dst[(((long)(b * 16 + hh) * 1024 + s) << 6) + d] = f2b(v);
                    }
        } else {
            // v: transpose via XOR-swizzled LDS, then coalesced d-row stores
            __syncthreads();           // all waves done reading A/B staging
            #pragma unroll
            for (int i = 0; i < MI; i++)
                #pragma unroll
                for (int j = 0; j < NJ; j++)
                    #pragma unroll
                    for (int r = 0; r < 4; r++) {
                        int nl = nw + j * 16 + lr;
                        int ml = mw + i * 16 + quad * 4 + r;
                        float v = acc[i][j][r] + b2f(bias[n0 + nl]);
                        Csh[nl * 128 + (((ml >> 3) ^ (nl & 15)) << 3) + (ml & 7)] = f2b(v);
                    }
            __syncthreads();
            const int nv0 = n0 - 2048;
            #pragma unroll
            for (int rep = 0; rep < 8; rep++) {
                int dd = rep * 16 + (tid >> 4);
                int sl = (tid & 15) * 8;
                int dg = nv0 + dd, hh = dg >> 6, dcol = dg & 63;
                u16x8 val = *(const u16x8*)&Csh[dd * 128 + ((((sl >> 3)) ^ (dd & 15)) << 3)];
                *(u16x8*)&vb[(((long)(b * 16 + hh) * 64 + dcol) << 10) + sbase + sl] = val;
            }
        }
        return;
    }

    u16* Cb;
    if (EPI == 5) Cb = C + (long)(bz >> 4) * (1 << 20) + (bz & 15) * 64;
    else          Cb = C + (long)bz * sC;

    #pragma unroll
    for (int i = 0; i < MI; i++) {
        #pragma unroll
        for (int j = 0; j < NJ; j++) {
            #pragma unroll
            for (int r = 0; r < 4; r++) {
                int gm = m0 + mw + i * 16 + quad * 4 + r;
                int gn = n0 + nw + j * 16 + lr;
                float v = acc[i][j][r];
                if (EPI == 5) {
                    Cb[(long)gm * ldc + gn] = f2b(v);
                } else if (EPI == 2) {
                    v += b2f(bias[gn]) + b2f(res[(long)gm * ldc + gn]);
                    Cb[(long)gm * ldc + gn] = f2b(v);
                } else if (EPI == 3) {
                    Cb[(long)gm * ldc + gn] = f2b(gelu_f(v + b2f(bias[gn])));
                } else if (EPI == 4) {
                    if (gn <= gm) Cb[(long)gm * ldc + gn] = f2b(v * 0.125f);
                } else if (EPI == 6) {
                    v += b2f(bias[gn]) + b2f(res[(long)gm * ldc + gn]);
                    long idx = (long)gm * ldc + gn;
                    if (*oflag) ((float*)oout)[idx] = v;
                    else        ((u16*)oout)[idx]   = f2b(v);
                } else if (EPI == 7) {
                    ((float*)oout)[(long)bz * sC + (long)gm * ldc + gn] = v;
                }
            }
        }
    }
}

extern "C" void kernel_launch(void* const* d_in, const int* in_sizes, int n_in,
                              void* d_out, int out_size, void* d_ws, size_t ws_size,
                              hipStream_t stream)
{
    const long MEG = 1L << 20;
    const long KI  = 1024;

    u16* ws = (u16*)d_ws;
    u16* xc    = ws;                    // 4Mi: bf16 x, becomes x2 in-place
    u16* winC  = ws + 4  * MEG;         // 3Mi
    u16* woutC = ws + 7  * MEG;         // 1Mi
    u16* wfcC  = ws + 8  * MEG;         // 4Mi
    u16* wprjC = ws + 12 * MEG;         // 4Mi
    u16* sm    = ws + 16 * MEG;
    u16* ln1g = sm + 0*4*KI, *ln1b = sm + 1*4*KI;
    u16* ln2g = sm + 2*4*KI, *ln2b = sm + 3*4*KI;
    u16* binC = sm + 4*4*KI;
    u16* boutC= sm + 5*4*KI;
    u16* bfcC = sm + 6*4*KI;
    u16* bprjC= sm + 7*4*KI;
    int* flag = (int*)(sm + 8*4*KI);
    u16* slotA = ws + 16 * MEG + 64 * KI;   // 4Mi: h / att / h2
    u16* qB    = slotA + 4  * MEG;
    u16* kB    = slotA + 8  * MEG;
    u16* vT    = slotA + 12 * MEG;
    u16* probs = slotA + 16 * MEG;      // chunk*(H,S,S); [0,16Mi) reused as act
    float* part = (float*)(probs + 16 * MEG);  // split-K partials (chunk=4 only)

    const long fixed_elems = 32 * MEG + 64 * KI;
    const long avail = (long)(ws_size / 2);
    int chunk = 1;
    if      (avail >= fixed_elems + 64 * MEG) chunk = 4;
    else if (avail >= fixed_elems + 32 * MEG) chunk = 2;
    const bool splitk = (chunk == 4);

    hipMemsetAsync((void*)flag, 0, sizeof(int), stream);
    detect_k<<<32, 256, 0, stream>>>((const u16*)d_in[0], flag);
    conv_w_k<<<12288, 256, 0, stream>>>(d_in[6], d_in[8], d_in[10], d_in[12],
                                        winC, flag);
    conv_small_k<<<52, 256, 0, stream>>>(d_in[2], d_in[3], d_in[4], d_in[5],
                                         d_in[7], d_in[9], d_in[11], d_in[13],
                                         sm, flag);

    u16* h   = slotA;
    u16* att = slotA;
    u16* h2  = slotA;
    u16* act = probs;

    // 1. LN1 (+x conversion)
    ln1x_k<<<4096, 256, 0, stream>>>(d_in[0], ln1g, ln1b, xc, h, flag);
    // 2. QKV projection
    gemm_bt<128, 1><<<dim3(24, 32, 1), 256, 0, stream>>>(
        h, winC, nullptr, binC, nullptr, qB, kB, vT,
        4096, 3072, 1024, 1024, 1024, 0, 0, 0, 0, nullptr, nullptr);
    // 3-6. attention
    for (int b0 = 0; b0 < 4; b0 += chunk) {
        gemm_bt<128, 4><<<dim3(8, 8, 16 * chunk), 256, 0, stream>>>(
            qB + b0 * MEG, kB + b0 * MEG, probs, nullptr, nullptr,
            nullptr, nullptr, nullptr,
            1024, 1024, 64, 64, 64, 1024, 65536, 65536, 1048576, nullptr, nullptr);
        smmean_k<<<1024 * chunk, 1024, 0, stream>>>(probs, d_out,
                                                    4 * MEG + b0 * MEG, flag);
        gemm_bt<64, 5><<<dim3(1, 8, 16 * chunk), 256, 0, stream>>>(
            probs, vT + b0 * MEG, att + b0 * MEG, nullptr, nullptr,
            nullptr, nullptr, nullptr,
            1024, 64, 1024, 1024, 1024, 1024, 1048576, 65536, 0, nullptr, nullptr);
    }
    // 7+8. x2 = x + att @ w_out^T + b_out; h2 = LN2(x2)
    if (splitk) {
        g8<7><<<dim3(4, 16, 2), 512, 0, stream>>>(
            att, woutC, nullptr, nullptr, part,
            512, 1024, 1024, 1024, 512, 512, 4 * MEG);
        redln_k<<<4096, 256, 0, stream>>>(part, 4 * MEG, boutC, xc, ln2g, ln2b, h2);
    } else {
        gemm_bt<128, 2><<<dim3(8, 32, 1), 256, 0, stream>>>(
            att, woutC, xc, boutC, xc, nullptr, nullptr, nullptr,
            4096, 1024, 1024, 1024, 1024, 1024, 0, 0, 0, nullptr, nullptr);
        ln_k<<<4096, 256, 0, stream>>>(xc, ln2g, ln2b, h2);
    }
    // 9. act = gelu(h2 @ w_fc^T + b_fc)   [256^2 8-phase kernel]
    g8<3><<<dim3(16, 16, 1), 512, 0, stream>>>(
        h2, wfcC, act, bfcC, nullptr,
        1024, 1024, 1024, 4096, 0, 0, 0);
    // 10. out = x2 + act @ w_proj^T + b_proj
    if (splitk) {
        g8<7><<<dim3(4, 16, 4), 512, 0, stream>>>(
            act, wprjC, nullptr, nullptr, part,
            1024, 4096, 4096, 1024, 1024, 1024, 4 * MEG);
        reduce_out_k<<<4096, 256, 0, stream>>>(part, 4 * MEG, bprjC, xc, d_out, flag);
    } else {
        gemm_bt<128, 6><<<dim3(8, 32, 1), 256, 0, stream>>>(
            act, wprjC, nullptr, bprjC, xc, nullptr, nullptr, nullptr,
            4096, 1024, 4096, 4096, 4096, 1024, 0, 0, 0, flag, d_out);
    }
}

// Round 7
// 409.791 us; speedup vs baseline: 1.2306x; 1.0066x over previous
//
#include <hip/hip_runtime.h>

typedef unsigned short u16;
typedef u16   u16x4 __attribute__((ext_vector_type(4)));
typedef u16   u16x8 __attribute__((ext_vector_type(8)));
typedef short s16x8 __attribute__((ext_vector_type(8)));
typedef float f32x4 __attribute__((ext_vector_type(4)));

__device__ __forceinline__ float b2f(u16 u) {
    union { unsigned int i; float f; } v; v.i = ((unsigned int)u) << 16; return v.f;
}
__device__ __forceinline__ u16 f2b(float f) {
    union { float f; unsigned int i; } v; v.f = f;
    unsigned int r = v.i + 0x7fffu + ((v.i >> 16) & 1u);
    return (u16)(r >> 16);
}
__device__ __forceinline__ float gelu_f(float x) {
    float z = 0.7978845608028654f * (x + 0.044715f * x * x * x);
    float e = __expf(2.0f * z);
    float t = 1.0f - 2.0f / (e + 1.0f);
    return 0.5f * x * (1.0f + t);
}
__device__ __forceinline__ void async16(const u16* g, u16* l) {
    __builtin_amdgcn_global_load_lds(
        (const __attribute__((address_space(1))) unsigned int*)g,
        (__attribute__((address_space(3))) unsigned int*)l,
        16, 0, 0);
}

#define FEN() asm volatile("" ::: "memory")
#define BARR() { FEN(); __builtin_amdgcn_s_barrier(); FEN(); }
#define VMC(N) asm volatile("s_waitcnt vmcnt(" #N ")" ::: "memory")

// ---- dtype detector: bf16-read exponent >= 2^60 anywhere => fp32 input
__global__ __launch_bounds__(256)
void detect_k(const u16* __restrict__ x, int* __restrict__ flag)
{
    int gid = blockIdx.x * 256 + threadIdx.x;
    const u16x8 u = *(const u16x8*)(x + (long)gid * 8);
    int bad = 0;
    #pragma unroll
    for (int e = 0; e < 8; e++) {
        int ex = (u[e] >> 7) & 0xFF;
        if (ex >= 187) bad = 1;
    }
    unsigned long long m = __ballot(bad != 0);
    if ((threadIdx.x & 63) == 0 && m != 0ull) atomicOr(flag, 1);
}

// ---- weight converter (vec4): w_in|w_out|w_fc|w_proj -> ws[4Mi..16Mi)
__global__ __launch_bounds__(256)
void conv_w_k(const void* __restrict__ s0, const void* __restrict__ s1,
              const void* __restrict__ s2, const void* __restrict__ s3,
              u16* __restrict__ dst, const int* __restrict__ flag)
{
    const long MEG = 1L << 20;
    long gid = ((long)blockIdx.x * 256 + threadIdx.x) * 4;   // < 12Mi
    const void* s; long off;
    if      (gid <  3*MEG) { s = s0; off = gid; }
    else if (gid <  4*MEG) { s = s1; off = gid - 3*MEG; }
    else if (gid <  8*MEG) { s = s2; off = gid - 4*MEG; }
    else                   { s = s3; off = gid - 8*MEG; }
    u16x4 o;
    if (*flag) {
        const float4 f = *(const float4*)((const float*)s + off);
        o[0] = f2b(f.x); o[1] = f2b(f.y); o[2] = f2b(f.z); o[3] = f2b(f.w);
    } else {
        o = *(const u16x4*)((const u16*)s + off);
    }
    *(u16x4*)(dst + gid) = o;
}

// ---- fused small-param converter into 4Ki-slotted region
__global__ __launch_bounds__(256)
void conv_small_k(const void* s0, const void* s1, const void* s2, const void* s3,
                  const void* s4, const void* s5, const void* s6, const void* s7,
                  u16* __restrict__ dst, const int* __restrict__ flag)
{
    int gid = blockIdx.x * 256 + threadIdx.x;          // < 13312
    int seg, off;
    if      (gid <  4096) { seg = gid >> 10;  off = gid & 1023; }
    else if (gid <  7168) { seg = 4; off = gid - 4096; }
    else if (gid <  8192) { seg = 5; off = gid - 7168; }
    else if (gid < 12288) { seg = 6; off = gid - 8192; }
    else                  { seg = 7; off = gid - 12288; }
    const void* srcs[8] = {s0, s1, s2, s3, s4, s5, s6, s7};
    const void* s = srcs[seg];
    dst[seg * 4096 + off] = (*flag) ? f2b(((const float*)s)[off]) : ((const u16*)s)[off];
}

// ---- LN1 fused with x conversion
__global__ __launch_bounds__(256)
void ln1x_k(const void* __restrict__ xraw, const u16* __restrict__ g,
            const u16* __restrict__ b, u16* __restrict__ xc,
            u16* __restrict__ o, const int* __restrict__ flag)
{
    long row = blockIdx.x;
    int tid = threadIdx.x;
    float v0, v1, v2, v3;
    if (*flag) {
        const float4 f = *(const float4*)((const float*)xraw + row * 1024 + tid * 4);
        v0 = b2f(f2b(f.x)); v1 = b2f(f2b(f.y));
        v2 = b2f(f2b(f.z)); v3 = b2f(f2b(f.w));
    } else {
        const u16x4 u = *(const u16x4*)((const u16*)xraw + row * 1024 + tid * 4);
        v0 = b2f(u[0]); v1 = b2f(u[1]); v2 = b2f(u[2]); v3 = b2f(u[3]);
    }
    u16x4 xv; xv[0] = f2b(v0); xv[1] = f2b(v1); xv[2] = f2b(v2); xv[3] = f2b(v3);
    *(u16x4*)(xc + row * 1024 + tid * 4) = xv;
    float s  = v0 + v1 + v2 + v3;
    float sq = v0*v0 + v1*v1 + v2*v2 + v3*v3;
    #pragma unroll
    for (int off = 32; off; off >>= 1) { s += __shfl_xor(s, off); sq += __shfl_xor(sq, off); }
    __shared__ float sm[8];
    int wid = tid >> 6, lane = tid & 63;
    if (lane == 0) { sm[wid] = s; sm[wid + 4] = sq; }
    __syncthreads();
    s  = sm[0] + sm[1] + sm[2] + sm[3];
    sq = sm[4] + sm[5] + sm[6] + sm[7];
    float mean = s * (1.0f / 1024.0f);
    float var  = sq * (1.0f / 1024.0f) - mean * mean;
    float rs   = rsqrtf(var + 1e-5f);
    u16x4 gg = *(const u16x4*)(g + tid * 4);
    u16x4 bb = *(const u16x4*)(b + tid * 4);
    u16x4 ov;
    ov[0] = f2b((v0 - mean) * rs * b2f(gg[0]) + b2f(bb[0]));
    ov[1] = f2b((v1 - mean) * rs * b2f(gg[1]) + b2f(bb[1]));
    ov[2] = f2b((v2 - mean) * rs * b2f(gg[2]) + b2f(bb[2]));
    ov[3] = f2b((v3 - mean) * rs * b2f(gg[3]) + b2f(bb[3]));
    *(u16x4*)(o + row * 1024 + tid * 4) = ov;
}

// ---- plain LN (fallback path)
__global__ __launch_bounds__(256)
void ln_k(const u16* __restrict__ x, const u16* __restrict__ g,
          const u16* __restrict__ b, u16* __restrict__ o)
{
    long row = blockIdx.x;
    int tid = threadIdx.x;
    const u16x4 u = *(const u16x4*)(x + row * 1024 + tid * 4);
    float v0 = b2f(u[0]), v1 = b2f(u[1]), v2 = b2f(u[2]), v3 = b2f(u[3]);
    float s  = v0 + v1 + v2 + v3;
    float sq = v0*v0 + v1*v1 + v2*v2 + v3*v3;
    #pragma unroll
    for (int off = 32; off; off >>= 1) { s += __shfl_xor(s, off); sq += __shfl_xor(sq, off); }
    __shared__ float sm[8];
    int wid = tid >> 6, lane = tid & 63;
    if (lane == 0) { sm[wid] = s; sm[wid + 4] = sq; }
    __syncthreads();
    s  = sm[0] + sm[1] + sm[2] + sm[3];
    sq = sm[4] + sm[5] + sm[6] + sm[7];
    float mean = s * (1.0f / 1024.0f);
    float var  = sq * (1.0f / 1024.0f) - mean * mean;
    float rs   = rsqrtf(var + 1e-5f);
    u16x4 gg = *(const u16x4*)(g + tid * 4);
    u16x4 bb = *(const u16x4*)(b + tid * 4);
    u16x4 ov;
    ov[0] = f2b((v0 - mean) * rs * b2f(gg[0]) + b2f(bb[0]));
    ov[1] = f2b((v1 - mean) * rs * b2f(gg[1]) + b2f(bb[1]));
    ov[2] = f2b((v2 - mean) * rs * b2f(gg[2]) + b2f(bb[2]));
    ov[3] = f2b((v3 - mean) * rs * b2f(gg[3]) + b2f(bb[3]));
    *(u16x4*)(o + row * 1024 + tid * 4) = ov;
}

// ---- fused split-K(2) reduce + LN2
__global__ __launch_bounds__(256)
void redln_k(const float* __restrict__ P, long slice,
             const u16* __restrict__ bias, u16* __restrict__ res,
             const u16* __restrict__ g, const u16* __restrict__ b,
             u16* __restrict__ o)
{
    long row = blockIdx.x;
    int tid = threadIdx.x;
    long i = row * 1024 + tid * 4;
    float4 v  = *(const float4*)(P + i);
    float4 p1 = *(const float4*)(P + slice + i);
    u16x4 bb = *(const u16x4*)(bias + tid * 4);
    u16x4 rr = *(const u16x4*)(res + i);
    float v0 = b2f(f2b(v.x + p1.x + b2f(bb[0]) + b2f(rr[0])));
    float v1 = b2f(f2b(v.y + p1.y + b2f(bb[1]) + b2f(rr[1])));
    float v2 = b2f(f2b(v.z + p1.z + b2f(bb[2]) + b2f(rr[2])));
    float v3 = b2f(f2b(v.w + p1.w + b2f(bb[3]) + b2f(rr[3])));
    u16x4 xv; xv[0] = f2b(v0); xv[1] = f2b(v1); xv[2] = f2b(v2); xv[3] = f2b(v3);
    *(u16x4*)(res + i) = xv;
    float s  = v0 + v1 + v2 + v3;
    float sq = v0*v0 + v1*v1 + v2*v2 + v3*v3;
    #pragma unroll
    for (int off = 32; off; off >>= 1) { s += __shfl_xor(s, off); sq += __shfl_xor(sq, off); }
    __shared__ float sm[8];
    int wid = tid >> 6, lane = tid & 63;
    if (lane == 0) { sm[wid] = s; sm[wid + 4] = sq; }
    __syncthreads();
    s  = sm[0] + sm[1] + sm[2] + sm[3];
    sq = sm[4] + sm[5] + sm[6] + sm[7];
    float mean = s * (1.0f / 1024.0f);
    float var  = sq * (1.0f / 1024.0f) - mean * mean;
    float rs   = rsqrtf(var + 1e-5f);
    u16x4 gg = *(const u16x4*)(g + tid * 4);
    u16x4 b2 = *(const u16x4*)(b + tid * 4);
    u16x4 ov;
    ov[0] = f2b((v0 - mean) * rs * b2f(gg[0]) + b2f(b2[0]));
    ov[1] = f2b((v1 - mean) * rs * b2f(gg[1]) + b2f(b2[1]));
    ov[2] = f2b((v2 - mean) * rs * b2f(gg[2]) + b2f(b2[2]));
    ov[3] = f2b((v3 - mean) * rs * b2f(gg[3]) + b2f(b2[3]));
    *(u16x4*)(o + row * 1024 + tid * 4) = ov;
}

// -------- Fused softmax (causal, in-place) + mean-over-heads ----------
__global__ __launch_bounds__(1024)
void smmean_k(u16* __restrict__ probs, void* __restrict__ ow, long ofs,
              const int* __restrict__ flag)
{
    const long MEG = 1L << 20;
    __shared__ float red[16 * 1024];
    int bl = blockIdx.x >> 10;           // batch within chunk
    int q  = blockIdx.x & 1023;
    int w = threadIdx.x >> 6, lane = threadIdx.x & 63;
    int tile_end = ((q >> 7) + 1) << 7;
    u16* row = probs + (((long)(bl * 16 + w)) << 20) + (long)q * 1024;
    float v[16];
    float m = -3.0e38f;
    #pragma unroll
    for (int c = 0; c < 2; c++) {
        int kb = (c * 64 + lane) * 8;
        if (kb <= q) {
            u16x8 u = *(const u16x8*)(row + kb);
            #pragma unroll
            for (int e = 0; e < 8; e++) {
                if (kb + e <= q) {
                    float f = b2f(u[e]);
                    v[c * 8 + e] = f;
                    m = fmaxf(m, f);
                } else v[c * 8 + e] = -3.0e38f;
            }
        } else {
            #pragma unroll
            for (int e = 0; e < 8; e++) v[c * 8 + e] = -3.0e38f;
        }
    }
    #pragma unroll
    for (int off = 32; off; off >>= 1) m = fmaxf(m, __shfl_xor(m, off));
    float s = 0.0f;
    #pragma unroll
    for (int t = 0; t < 16; t++) {
        float e = (v[t] > -1.0e38f) ? __expf(v[t] - m) : 0.0f;
        v[t] = e; s += e;
    }
    #pragma unroll
    for (int off = 32; off; off >>= 1) s += __shfl_xor(s, off);
    float inv = 1.0f / s;
    #pragma unroll
    for (int c = 0; c < 2; c++) {
        int kb = (c * 64 + lane) * 8;
        float p[8];
        #pragma unroll
        for (int e = 0; e < 8; e++) p[e] = v[c * 8 + e] * inv;
        #pragma unroll
        for (int e = 0; e < 8; e++) red[w * 1024 + kb + e] = p[e];
        if (kb < tile_end) {
            u16x8 o;
            #pragma unroll
            for (int e = 0; e < 8; e++) o[e] = f2b(p[e]);
            *(u16x8*)(row + kb) = o;
        }
    }
    __syncthreads();
    int t = threadIdx.x;
    float acc = 0.0f;
    #pragma unroll
    for (int h = 0; h < 16; h++) acc += red[h * 1024 + t];
    acc *= 0.0625f;
    long idx = ofs + (long)bl * MEG + (long)q * 1024 + t;
    if (*flag) ((float*)ow)[idx] = acc;
    else       ((u16*)ow)[idx]   = f2b(acc);
}

// -------- split-K(4) reduce for final output --------
__global__ __launch_bounds__(256)
void reduce_out_k(const float* __restrict__ P, long slice,
                  const u16* __restrict__ bias, const u16* __restrict__ res,
                  void* __restrict__ out, const int* __restrict__ flag)
{
    long i = ((long)blockIdx.x * 256 + threadIdx.x) * 4;
    int gn = (int)(i & 1023);
    float4 v = *(const float4*)(P + i);
    #pragma unroll
    for (int s = 1; s < 4; s++) {
        const float4 p = *(const float4*)(P + (long)s * slice + i);
        v.x += p.x; v.y += p.y; v.z += p.z; v.w += p.w;
    }
    u16x4 bb = *(const u16x4*)(bias + gn);
    u16x4 rr = *(const u16x4*)(res + i);
    v.x += b2f(bb[0]) + b2f(rr[0]);
    v.y += b2f(bb[1]) + b2f(rr[1]);
    v.z += b2f(bb[2]) + b2f(rr[2]);
    v.w += b2f(bb[3]) + b2f(rr[3]);
    if (*flag) {
        *(float4*)((float*)out + i) = v;
    } else {
        u16x4 o;
        o[0] = f2b(v.x); o[1] = f2b(v.y); o[2] = f2b(v.z); o[3] = f2b(v.w);
        *(u16x4*)((u16*)out + i) = o;
    }
}

// ======== g8: 256x256x(BK=64) 8-phase deep-pipelined GEMM =============
// C[m,n] = sum_k A[m,k] * Bt[n,k]  (+ epilogue).  EPI: 3 gelu(+bias)->bf16,
// 7 split-K fp32 partial.  Requires NT = K/64 even and >= 2.
// Even K-tiles -> buf0, odd -> buf1; 4 (Ahalf,Bhalf) phases per K-tile:
//   P1 reads A0,B0; P2 reads B1; P3 reads A1; P4 register-only.
// Staging slots (R6): P1:(t+1).B1  P2:(t+2).A0  P3:(t+2).B0  P4:(t+1).A1.
// Waits: VMC(8)@end-P1 (retires (t).B1, 4 phases old), VMC(4)@end-P2
// (retires (t).A1, 2 phases old, + (t+1).A0/B0). Never drained in-loop.
// R7: NO manual lgkmcnt/sched_barrier — ds_reads are plain C++ loads, so
// the compiler emits minimal staged lgkmcnt(N) waits and interleaves
// MFMA/addr-VALU with the LDS drain (m97/m141 lesson: pinning the order
// with lgkmcnt(0)+sched_barrier(0) serializes drain->MFMA every phase).
// Ledger integrity: BARR()/VMC() carry asm memory clobbers, so ds_read /
// global_load_lds (memory ops) cannot migrate across them; every ds_read's
// result is consumed by MFMA before the end-phase barrier, so all reads
// complete before any wave passes it (staging-overwrite race stays closed).
// In-row XOR swizzle slot^=(row&7) on the global source (keeps 128B/8-lane
// coalescing) and on the ds_read chunk index -> conflict-free ds_read_b128.
template<int EPI>
__global__ __launch_bounds__(512, 2)
void g8(const u16* __restrict__ A, const u16* __restrict__ Bt,
        u16* __restrict__ C, const u16* __restrict__ bias,
        float* __restrict__ Cf,
        int K, int lda, int ldb, int ldc,
        long sA, long sB, long sC)
{
    __shared__ alignas(16) u16 shA[2 * 16384];   // 64 KB
    __shared__ alignas(16) u16 shB[2 * 16384];   // 64 KB

    const int tid = threadIdx.x;
    int tn = blockIdx.x, tm = blockIdx.y;
    const int bz = blockIdx.z;
    {   // XCD-aware swizzle; requires gridDim.y % 8 == 0
        int L = blockIdx.y * gridDim.x + blockIdx.x;
        int xcd = L & 7, idx = L >> 3;
        tn = idx % gridDim.x;
        tm = (idx / gridDim.x) * 8 + xcd;
    }
    const u16* Ab = A + (long)bz * sA;
    const u16* Bb = Bt + (long)bz * sB;
    const int m0 = tm * 256, n0 = tn * 256;
    const int NT = K >> 6;

    const int w = tid >> 6, lane = tid & 63;
    const int lr = lane & 15, quad = lane >> 4, sw = lane & 7;
    const int wm16 = (w >> 2) * 16, wn16 = (w & 3) * 16;

    auto stageH = [&](int tile, int isB, int half) {
        const u16* src = isB ? Bb : Ab;
        const int ld = isB ? ldb : lda;
        const int r0 = (isB ? n0 : m0) + half * 128;
        u16* dbase = (isB ? shB : shA) + (tile & 1) * 16384 + half * 8192;
        const long kk = (long)tile << 6;
        #pragma unroll
        for (int L2 = 0; L2 < 2; L2++) {
            int c = L2 * 512 + tid;
            int rl = c >> 3, sl = c & 7;
            int kc = sl ^ (rl & 7);
            async16(src + (long)(r0 + rl) * ld + kk + kc * 8, dbase + c * 8);
        }
    };

    f32x4 acc[2][4][2][2] = {};
    s16x8 aF[4][2], b0F[2][2], b1F[2][2];

    auto rdA = [&](int buf, int ih) {
        #pragma unroll
        for (int q = 0; q < 4; q++)
            #pragma unroll
            for (int ks = 0; ks < 2; ks++)
                aF[q][ks] = *(const s16x8*)&shA[buf * 16384 + ih * 8192
                    + (q * 32 + wm16 + lr) * 64 + ((ks * 4 + quad) ^ sw) * 8];
    };
    auto rdB = [&](s16x8 (&bF)[2][2], int buf, int jh) {
        #pragma unroll
        for (int r = 0; r < 2; r++)
            #pragma unroll
            for (int ks = 0; ks < 2; ks++)
                bF[r][ks] = *(const s16x8*)&shB[buf * 16384 + jh * 8192
                    + (r * 64 + wn16 + lr) * 64 + ((ks * 4 + quad) ^ sw) * 8];
    };

#define MM(IH, JH, BF) do { \
    __builtin_amdgcn_s_setprio(1); \
    _Pragma("unroll") \
    for (int q = 0; q < 4; q++) \
        _Pragma("unroll") \
        for (int r = 0; r < 2; r++) \
            _Pragma("unroll") \
            for (int ks = 0; ks < 2; ks++) \
                acc[IH][q][JH][r] = __builtin_amdgcn_mfma_f32_16x16x32_bf16( \
                    aF[q][ks], BF[r][ks], acc[IH][q][JH][r], 0, 0, 0); \
    __builtin_amdgcn_s_setprio(0); \
} while (0)

    // prologue — issue order mirrors steady-state FIFO slots:
    // t0.A0, t0.B0, t0.B1, t1.A0, t1.B0, t0.A1 ; VMC(8) retires t0.A0,B0
    stageH(0, 0, 0); stageH(0, 1, 0); stageH(0, 1, 1);
    stageH(1, 0, 0); stageH(1, 1, 0); stageH(0, 0, 1);
    VMC(8); BARR();

    for (int t = 0; t < NT - 2; ++t) {
        const int buf = t & 1;
        // P1: read A0,B0; stage (t+1).B1
        rdA(buf, 0); rdB(b0F, buf, 0); stageH(t + 1, 1, 1);
        BARR(); MM(0, 0, b0F);
        FEN(); VMC(8); BARR();
        // P2: read B1; stage (t+2).A0
        rdB(b1F, buf, 1); stageH(t + 2, 0, 0);
        BARR(); MM(0, 1, b1F);
        FEN(); VMC(4); BARR();
        // P3: read A1; stage (t+2).B0
        rdA(buf, 1); stageH(t + 2, 1, 0);
        BARR(); MM(1, 0, b0F);
        BARR();
        // P4: stage (t+1).A1
        stageH(t + 1, 0, 1);
        BARR(); MM(1, 1, b1F);
        BARR();
    }

    // ---- peeled tile NT-2 ----
    {
        const int buf = (NT - 2) & 1;
        rdA(buf, 0); rdB(b0F, buf, 0); stageH(NT - 1, 1, 1);   // P1
        BARR(); MM(0, 0, b0F);
        FEN(); VMC(8); BARR();                                 // retires (NT-2).B1
        rdB(b1F, buf, 1);                                      // P2 (no stage)
        BARR(); MM(0, 1, b1F);
        FEN(); VMC(2); BARR();                                 // retires (NT-2).A1 (+older)
        rdA(buf, 1);                                           // P3 (no stage)
        BARR(); MM(1, 0, b0F);
        BARR();
        stageH(NT - 1, 0, 1);                                  // P4
        BARR(); MM(1, 1, b1F);
        BARR();
    }
    // ---- peeled tile NT-1 ----
    {
        const int buf = (NT - 1) & 1;
        rdA(buf, 0); rdB(b0F, buf, 0);                         // P1
        BARR(); MM(0, 0, b0F);
        FEN(); VMC(2); BARR();                                 // retires (NT-1).B1
        rdB(b1F, buf, 1);                                      // P2
        BARR(); MM(0, 1, b1F);
        FEN(); VMC(0); BARR();                                 // retires (NT-1).A1
        rdA(buf, 1);                                           // P3
        BARR(); MM(1, 0, b0F);
        BARR();
        MM(1, 1, b1F);                                         // P4
    }
#undef MM

    // epilogue
    #pragma unroll
    for (int ih = 0; ih < 2; ih++)
        #pragma unroll
        for (int q = 0; q < 4; q++)
            #pragma unroll
            for (int jh = 0; jh < 2; jh++)
                #pragma unroll
                for (int r = 0; r < 2; r++)
                    #pragma unroll
                    for (int rr = 0; rr < 4; rr++) {
                        int gm = m0 + ih * 128 + q * 32 + wm16 + quad * 4 + rr;
                        int gn = n0 + jh * 128 + r * 64 + wn16 + lr;
                        float v = acc[ih][q][jh][r][rr];
                        if (EPI == 3) {
                            C[(long)gm * ldc + gn] = f2b(gelu_f(v + b2f(bias[gn])));
                        } else {
                            Cf[(long)bz * sC + (long)gm * ldc + gn] = v;
                        }
                    }
}

// ---------------- gemm_bt: C[m,n] = sum_k A[m,k]*Bt[n,k] + epilogue ---
// (128x128 2-phase kernel; kept for QKV/scores/PV/fallback paths)
template<int BN, int EPI>
__global__ __launch_bounds__(256)
void gemm_bt(const u16* __restrict__ A, const u16* __restrict__ Bt,
             u16* __restrict__ C, const u16* __restrict__ bias,
             const u16* __restrict__ res,
             u16* __restrict__ qb, u16* __restrict__ kb, u16* __restrict__ vb,
             int M, int N, int K, int lda, int ldb, int ldc,
             long sA, long sB, long sC,
             const int* __restrict__ oflag, void* __restrict__ oout)
{
    constexpr int BM = 128, BK = 32;
    constexpr int WROWS = (BN == 128) ? 2 : 4;
    constexpr int WCOLS = (BN == 128) ? 2 : 1;
    constexpr int WM = BM / WROWS, WN = BN / WCOLS;
    constexpr int MI = WM / 16, NJ = WN / 16;
    constexpr int BCH = BN * BK / 8 / 256;
    constexpr int SHSZ = 2 * BM * BK + 2 * BN * BK;   // u16 units

    __shared__ alignas(16) u16 shmem[SHSZ];
    u16* AshB = shmem;                 // 2 × BM*BK
    u16* BshB = shmem + 2 * BM * BK;   // 2 × BN*BK
    u16* Csh  = shmem;                 // EPI==1 epilogue reuse (16384 u16)

    const int tid = threadIdx.x;
    int tn = blockIdx.x, tm = blockIdx.y;
    const int bz = blockIdx.z;
    if (EPI == 4 && tn > tm) return;

    // XCD-aware swizzle (A-panel locality); requires gridDim.y % 8 == 0
    if (EPI == 1 || EPI == 2 || EPI == 3 || EPI == 6 || EPI == 7) {
        int L = blockIdx.y * gridDim.x + blockIdx.x;
        int xcd = L & 7, idx = L >> 3;
        tn = idx % gridDim.x;
        tm = (idx / gridDim.x) * 8 + xcd;
    }

    const u16* Ab = A + (long)bz * sA;
    const u16* Bb = Bt + (long)bz * sB;

    const int m0 = tm * BM, n0 = tn * BN;
    const int kEff = (EPI == 5) ? (((tm + 1) * BM < K) ? (tm + 1) * BM : K) : K;

    const int w = tid >> 6, lane = tid & 63;
    const int wrow = w % WROWS, wcol = w / WROWS;
    const int mw = wrow * WM, nw = wcol * WN;
    const int lr = lane & 15, quad = lane >> 4;

    const int ca0 = tid, ca1 = 256 + tid;
    const int cb1 = 256 + tid;

    // staging: chunk c -> row c>>2; global k-chunk = (c&3) ^ ((c>>3)&3)
    const int ar0 = ca0 >> 2, ac0 = (((ca0 & 3) ^ ((ca0 >> 3) & 3))) * 8;
    const int ar1 = ca1 >> 2, ac1 = (((ca1 & 3) ^ ((ca1 >> 3) & 3))) * 8;
    const int br0 = tid >> 2, bc0 = (((tid & 3) ^ ((tid >> 3) & 3))) * 8;
    const int br1 = cb1 >> 2, bc1 = (((cb1 & 3) ^ ((cb1 >> 3) & 3))) * 8;

    auto stage = [&](int buf, int k0) {
        async16(Ab + (long)(m0 + ar0) * lda + k0 + ac0, &AshB[buf * BM * BK + ca0 * 8]);
        async16(Ab + (long)(m0 + ar1) * lda + k0 + ac1, &AshB[buf * BM * BK + ca1 * 8]);
        async16(Bb + (long)(n0 + br0) * ldb + k0 + bc0, &BshB[buf * BN * BK + tid * 8]);
        if (BCH == 2)
            async16(Bb + (long)(n0 + br1) * ldb + k0 + bc1, &BshB[buf * BN * BK + cb1 * 8]);
    };

    f32x4 acc[MI][NJ] = {};

    const int foff = (quad ^ ((lr >> 1) & 3)) * 8;

    stage(0, 0);
    int cur = 0;
    for (int k0 = 0; k0 < kEff; k0 += BK) {
        __syncthreads();
        if (k0 + BK < kEff) stage(cur ^ 1, k0 + BK);

        s16x8 af[MI], bfr[NJ];
        #pragma unroll
        for (int i = 0; i < MI; i++)
            af[i] = *(const s16x8*)&AshB[cur * BM * BK + (mw + i * 16 + lr) * BK + foff];
        #pragma unroll
        for (int j = 0; j < NJ; j++)
            bfr[j] = *(const s16x8*)&BshB[cur * BN * BK + (nw + j * 16 + lr) * BK + foff];
        #pragma unroll
        for (int i = 0; i < MI; i++)
            #pragma unroll
            for (int j = 0; j < NJ; j++)
                acc[i][j] = __builtin_amdgcn_mfma_f32_16x16x32_bf16(af[i], bfr[j], acc[i][j], 0, 0, 0);
        cur ^= 1;
    }

    if (EPI == 1) {
        const int sel = n0 >> 10;      // 0=q 1=k 2=v (tile within one section)
        const int b = m0 >> 10, sbase = m0 & 1023;
        if (sel < 2) {
            u16* dst = (sel == 0) ? qb : kb;
            #pragma unroll
            for (int i = 0; i < MI; i++)
                #pragma unroll
                for (int j = 0; j < NJ; j++)
                    #pragma unroll
                    for (int r = 0; r < 4; r++) {
                        int gm = m0 + mw + i * 16 + quad * 4 + r;
                        int gn = n0 + nw + j * 16 + lr;
                        float v = acc[i][j][r] + b2f(bias[gn]);
                        int s = gm & 1023, nn = gn & 1023, hh = nn >> 6, d = nn & 63;
                        dst[(((long)(b * 16 + hh) * 1024 + s) << 6) + d] = f2b(v);
                    }
        } else {
            // v: transpose via XOR-swizzled LDS, then coalesced d-row stores
            __syncthreads();           // all waves done reading A/B staging
            #pragma unroll
            for (int i = 0; i < MI; i++)
                #pragma unroll
                for (int j = 0; j < NJ; j++)
                    #pragma unroll
                    for (int r = 0; r < 4; r++) {
                        int nl = nw + j * 16 + lr;
                        int ml = mw + i * 16 + quad * 4 + r;
                        float v = acc[i][j][r] + b2f(bias[n0 + nl]);
                        Csh[nl * 128 + (((ml >> 3) ^ (nl & 15)) << 3) + (ml & 7)] = f2b(v);
                    }
            __syncthreads();
            const int nv0 = n0 - 2048;
            #pragma unroll
            for (int rep = 0; rep < 8; rep++) {
                int dd = rep * 16 + (tid >> 4);
                int sl = (tid & 15) * 8;
                int dg = nv0 + dd, hh = dg >> 6, dcol = dg & 63;
                u16x8 val = *(const u16x8*)&Csh[dd * 128 + ((((sl >> 3)) ^ (dd & 15)) << 3)];
                *(u16x8*)&vb[(((long)(b * 16 + hh) * 64 + dcol) << 10) + sbase + sl] = val;
            }
        }
        return;
    }

    u16* Cb;
    if (EPI == 5) Cb = C + (long)(bz >> 4) * (1 << 20) + (bz & 15) * 64;
    else          Cb = C + (long)bz * sC;

    #pragma unroll
    for (int i = 0; i < MI; i++) {
        #pragma unroll
        for (int j = 0; j < NJ; j++) {
            #pragma unroll
            for (int r = 0; r < 4; r++) {
                int gm = m0 + mw + i * 16 + quad * 4 + r;
                int gn = n0 + nw + j * 16 + lr;
                float v = acc[i][j][r];
                if (EPI == 5) {
                    Cb[(long)gm * ldc + gn] = f2b(v);
                } else if (EPI == 2) {
                    v += b2f(bias[gn]) + b2f(res[(long)gm * ldc + gn]);
                    Cb[(long)gm * ldc + gn] = f2b(v);
                } else if (EPI == 3) {
                    Cb[(long)gm * ldc + gn] = f2b(gelu_f(v + b2f(bias[gn])));
                } else if (EPI == 4) {
                    if (gn <= gm) Cb[(long)gm * ldc + gn] = f2b(v * 0.125f);
                } else if (EPI == 6) {
                    v += b2f(bias[gn]) + b2f(res[(long)gm * ldc + gn]);
                    long idx = (long)gm * ldc + gn;
                    if (*oflag) ((float*)oout)[idx] = v;
                    else        ((u16*)oout)[idx]   = f2b(v);
                } else if (EPI == 7) {
                    ((float*)oout)[(long)bz * sC + (long)gm * ldc + gn] = v;
                }
            }
        }
    }
}

extern "C" void kernel_launch(void* const* d_in, const int* in_sizes, int n_in,
                              void* d_out, int out_size, void* d_ws, size_t ws_size,
                              hipStream_t stream)
{
    const long MEG = 1L << 20;
    const long KI  = 1024;

    u16* ws = (u16*)d_ws;
    u16* xc    = ws;                    // 4Mi: bf16 x, becomes x2 in-place
    u16* winC  = ws + 4  * MEG;         // 3Mi
    u16* woutC = ws + 7  * MEG;         // 1Mi
    u16* wfcC  = ws + 8  * MEG;         // 4Mi
    u16* wprjC = ws + 12 * MEG;         // 4Mi
    u16* sm    = ws + 16 * MEG;
    u16* ln1g = sm + 0*4*KI, *ln1b = sm + 1*4*KI;
    u16* ln2g = sm + 2*4*KI, *ln2b = sm + 3*4*KI;
    u16* binC = sm + 4*4*KI;
    u16* boutC= sm + 5*4*KI;
    u16* bfcC = sm + 6*4*KI;
    u16* bprjC= sm + 7*4*KI;
    int* flag = (int*)(sm + 8*4*KI);
    u16* slotA = ws + 16 * MEG + 64 * KI;   // 4Mi: h / att / h2
    u16* qB    = slotA + 4  * MEG;
    u16* kB    = slotA + 8  * MEG;
    u16* vT    = slotA + 12 * MEG;
    u16* probs = slotA + 16 * MEG;      // chunk*(H,S,S); [0,16Mi) reused as act
    float* part = (float*)(probs + 16 * MEG);  // split-K partials (chunk=4 only)

    const long fixed_elems = 32 * MEG + 64 * KI;
    const long avail = (long)(ws_size / 2);
    int chunk = 1;
    if      (avail >= fixed_elems + 64 * MEG) chunk = 4;
    else if (avail >= fixed_elems + 32 * MEG) chunk = 2;
    const bool splitk = (chunk == 4);

    hipMemsetAsync((void*)flag, 0, sizeof(int), stream);
    detect_k<<<32, 256, 0, stream>>>((const u16*)d_in[0], flag);
    conv_w_k<<<12288, 256, 0, stream>>>(d_in[6], d_in[8], d_in[10], d_in[12],
                                        winC, flag);
    conv_small_k<<<52, 256, 0, stream>>>(d_in[2], d_in[3], d_in[4], d_in[5],
                                         d_in[7], d_in[9], d_in[11], d_in[13],
                                         sm, flag);

    u16* h   = slotA;
    u16* att = slotA;
    u16* h2  = slotA;
    u16* act = probs;

    // 1. LN1 (+x conversion)
    ln1x_k<<<4096, 256, 0, stream>>>(d_in[0], ln1g, ln1b, xc, h, flag);
    // 2. QKV projection
    gemm_bt<128, 1><<<dim3(24, 32, 1), 256, 0, stream>>>(
        h, winC, nullptr, binC, nullptr, qB, kB, vT,
        4096, 3072, 1024, 1024, 1024, 0, 0, 0, 0, nullptr, nullptr);
    // 3-6. attention
    for (int b0 = 0; b0 < 4; b0 += chunk) {
        gemm_bt<128, 4><<<dim3(8, 8, 16 * chunk), 256, 0, stream>>>(
            qB + b0 * MEG, kB + b0 * MEG, probs, nullptr, nullptr,
            nullptr, nullptr, nullptr,
            1024, 1024, 64, 64, 64, 1024, 65536, 65536, 1048576, nullptr, nullptr);
        smmean_k<<<1024 * chunk, 1024, 0, stream>>>(probs, d_out,
                                                    4 * MEG + b0 * MEG, flag);
        gemm_bt<64, 5><<<dim3(1, 8, 16 * chunk), 256, 0, stream>>>(
            probs, vT + b0 * MEG, att + b0 * MEG, nullptr, nullptr,
            nullptr, nullptr, nullptr,
            1024, 64, 1024, 1024, 1024, 1024, 1048576, 65536, 0, nullptr, nullptr);
    }
    // 7+8. x2 = x + att @ w_out^T + b_out; h2 = LN2(x2)
    if (splitk) {
        g8<7><<<dim3(4, 16, 2), 512, 0, stream>>>(
            att, woutC, nullptr, nullptr, part,
            512, 1024, 1024, 1024, 512, 512, 4 * MEG);
        redln_k<<<4096, 256, 0, stream>>>(part, 4 * MEG, boutC, xc, ln2g, ln2b, h2);
    } else {
        gemm_bt<128, 2><<<dim3(8, 32, 1), 256, 0, stream>>>(
            att, woutC, xc, boutC, xc, nullptr, nullptr, nullptr,
            4096, 1024, 1024, 1024, 1024, 1024, 0, 0, 0, nullptr, nullptr);
        ln_k<<<4096, 256, 0, stream>>>(xc, ln2g, ln2b, h2);
    }
    // 9. act = gelu(h2 @ w_fc^T + b_fc)   [256^2 8-phase kernel]
    g8<3><<<dim3(16, 16, 1), 512, 0, stream>>>(
        h2, wfcC, act, bfcC, nullptr,
        1024, 1024, 1024, 4096, 0, 0, 0);
    // 10. out = x2 + act @ w_proj^T + b_proj
    if (splitk) {
        g8<7><<<dim3(4, 16, 4), 512, 0, stream>>>(
            act, wprjC, nullptr, nullptr, part,
            1024, 4096, 4096, 1024, 1024, 1024, 4 * MEG);
        reduce_out_k<<<4096, 256, 0, stream>>>(part, 4 * MEG, bprjC, xc, d_out, flag);
    } else {
        gemm_bt<128, 6><<<dim3(8, 32, 1), 256, 0, stream>>>(
            act, wprjC, nullptr, bprjC, xc, nullptr, nullptr, nullptr,
            4096, 1024, 4096, 4096, 4096, 1024, 0, 0, 0, flag, d_out);
    }
}